// Round 1
// baseline (2398.639 us; speedup 1.0000x reference)
//
#include <hip/hip_runtime.h>
#include <math.h>

#define BB   128
#define DECD 512
#define E2D  1024
#define EMBD 256
#define S1D  200
#define S2D  200
#define SJD  400
#define VV   50000
#define NEGV (-1e10f)

// ---- workspace layout (float offsets) ----
enum : size_t {
  O_EMB = 0,               // 128*256   = 32768
  O_HWA = 32768,           // 128*512   = 65536
  O_SCJ = 98304,           // 128*400   = 51200
  O_WGT = 149504,          // 128*1024  = 131072
  O_X   = 280576,          // 128*1280  = 163840
  O_GX  = 444416,          // 128*1536  = 196608
  O_GH  = 641024,          // 128*1536  = 196608
  O_ST  = 837632,          // 128*1536  = 196608
  O_HWC = 1034240,         // 128*512   = 65536
  O_SCC = 1099776,         // 128*200   = 25600
  O_PG  = 1125376          // 128
};

__global__ __launch_bounds__(256) void k_emb(const int* __restrict__ inp,
    const float* __restrict__ table, float* __restrict__ emb) {
  int b = blockIdx.x;
  int t = threadIdx.x;
  emb[(size_t)b*EMBD + t] = table[(size_t)inp[b]*EMBD + t];
}

// out[b][d] = sum_k h[b][k] * W[k][d] + bias[d]   (W row-major [>=512][512], top 512 rows used)
__global__ __launch_bounds__(256) void k_partial(const float* __restrict__ h,
    const float* __restrict__ W, const float* __restrict__ bias,
    float* __restrict__ out) {
  int b = blockIdx.y;
  int d = blockIdx.x * 256 + threadIdx.x;
  const float* hr = h + (size_t)b * DECD;
  float acc = bias[d];
  #pragma unroll 8
  for (int k = 0; k < DECD; ++k) acc += hr[k] * W[(size_t)k * DECD + d];
  out[(size_t)b * DECD + d] = acc;
}

// scores[b][s] = sum_d tanh( hW[b][d] + enc[s][b][:] @ Wenc[:,d] ) * v[d]
// block: one s, 16 consecutive b.  grid = S*8 blocks.
__global__ __launch_bounds__(256) void k_scores(
    const float* __restrict__ enc1, const float* __restrict__ enc2,
    const float* __restrict__ Wenc,   // [1024][512] row-major
    const float* __restrict__ hW,     // [128][512]
    const float* __restrict__ v,      // [512]
    float* __restrict__ scores, int sld) {
  __shared__ float Xs[16][E2D];   // 64 KB
  int tid = threadIdx.x;
  int s  = blockIdx.x >> 3;
  int b0 = (blockIdx.x & 7) * 16;
  const float* encbase = (s < S1D) ? (enc1 + (size_t)s * BB * E2D)
                                   : (enc2 + (size_t)(s - S1D) * BB * E2D);
  #pragma unroll
  for (int r = 0; r < 16; ++r) {
    const float4* src = (const float4*)(encbase + (size_t)(b0 + r) * E2D);
    ((float4*)&Xs[r][0])[tid] = src[tid];
  }
  __syncthreads();

  int d1 = tid, d2 = tid + 256;
  const float* W1 = Wenc + d1;
  const float* W2 = Wenc + d2;
  float acc0[16], acc1[16];
  #pragma unroll
  for (int r = 0; r < 16; ++r) { acc0[r] = 0.f; acc1[r] = 0.f; }

  for (int e0 = 0; e0 < E2D; e0 += 4) {
    float w10 = W1[(size_t)(e0 + 0) * DECD];
    float w11 = W1[(size_t)(e0 + 1) * DECD];
    float w12 = W1[(size_t)(e0 + 2) * DECD];
    float w13 = W1[(size_t)(e0 + 3) * DECD];
    float w20 = W2[(size_t)(e0 + 0) * DECD];
    float w21 = W2[(size_t)(e0 + 1) * DECD];
    float w22 = W2[(size_t)(e0 + 2) * DECD];
    float w23 = W2[(size_t)(e0 + 3) * DECD];
    #pragma unroll
    for (int r = 0; r < 16; ++r) {
      float4 xv = *(const float4*)&Xs[r][e0];
      acc0[r] += xv.x * w10 + xv.y * w11 + xv.z * w12 + xv.w * w13;
      acc1[r] += xv.x * w20 + xv.y * w21 + xv.z * w22 + xv.w * w23;
    }
  }
  __syncthreads();            // done with Xs as data; reuse as reduction buffer

  float v1 = v[d1], v2 = v[d2];
  float* red = &Xs[0][0];
  int lane = tid & 63, wid = tid >> 6;
  #pragma unroll
  for (int r = 0; r < 16; ++r) {
    float hv1 = hW[(size_t)(b0 + r) * DECD + d1];
    float hv2 = hW[(size_t)(b0 + r) * DECD + d2];
    float part = tanhf(acc0[r] + hv1) * v1 + tanhf(acc1[r] + hv2) * v2;
    #pragma unroll
    for (int off = 32; off > 0; off >>= 1) part += __shfl_down(part, off, 64);
    if (lane == 0) red[r * 4 + wid] = part;
  }
  __syncthreads();
  if (tid < 16) {
    float sres = red[tid*4+0] + red[tid*4+1] + red[tid*4+2] + red[tid*4+3];
    scores[(size_t)(b0 + tid) * sld + s] = sres;
  }
}

// masked softmax over s (row layout [b][S]); mode 0: joint (m1=mask1,m2=mask2), mode 1: copy (mask1*triple)
__global__ __launch_bounds__(256) void k_softmax_s(float* __restrict__ sc, int S,
    const int* __restrict__ m1, const int* __restrict__ m2, int mode) {
  int b = blockIdx.x, tid = threadIdx.x;
  __shared__ float sm[4];
  int s0 = tid, s2 = tid + 256;
  float a0 = -INFINITY, a1 = -INFINITY;
  if (s0 < S) {
    int msk = (mode == 0) ? ((s0 < S1D) ? m1[b*S1D + s0] : m2[b*S2D + (s0 - S1D)])
                          : (m1[b*S1D + s0] * m2[b*S1D + s0]);
    a0 = msk ? sc[(size_t)b*S + s0] : NEGV;
  }
  if (s2 < S) {
    int msk = (mode == 0) ? ((s2 < S1D) ? m1[b*S1D + s2] : m2[b*S2D + (s2 - S1D)])
                          : (m1[b*S1D + s2] * m2[b*S1D + s2]);
    a1 = msk ? sc[(size_t)b*S + s2] : NEGV;
  }
  float vmax = fmaxf(a0, a1);
  #pragma unroll
  for (int off = 32; off > 0; off >>= 1) vmax = fmaxf(vmax, __shfl_down(vmax, off, 64));
  int lane = tid & 63, wid = tid >> 6;
  if (lane == 0) sm[wid] = vmax;
  __syncthreads();
  vmax = fmaxf(fmaxf(sm[0], sm[1]), fmaxf(sm[2], sm[3]));
  __syncthreads();
  float lsum = 0.f;
  if (s0 < S) lsum += expf(a0 - vmax);
  if (s2 < S) lsum += expf(a1 - vmax);
  #pragma unroll
  for (int off = 32; off > 0; off >>= 1) lsum += __shfl_down(lsum, off, 64);
  if (lane == 0) sm[wid] = lsum;
  __syncthreads();
  float inv = 1.0f / (sm[0] + sm[1] + sm[2] + sm[3]);
  if (s0 < S) sc[(size_t)b*S + s0] = expf(a0 - vmax) * inv;
  if (s2 < S) sc[(size_t)b*S + s2] = expf(a1 - vmax) * inv;
}

// weighted[b][e] = sum_s a[b][s] * enc[s][b][e]
__global__ __launch_bounds__(256) void k_weighted(const float* __restrict__ enc1,
    const float* __restrict__ enc2, const float* __restrict__ a,
    float* __restrict__ out) {
  int b = blockIdx.x;
  int e = blockIdx.y * 256 + threadIdx.x;
  const float* arow = a + (size_t)b * SJD;
  float acc = 0.f;
  #pragma unroll 4
  for (int s = 0; s < SJD; ++s) {
    const float* ep = (s < S1D) ? (enc1 + ((size_t)s * BB + b) * E2D)
                                : (enc2 + ((size_t)(s - S1D) * BB + b) * E2D);
    acc += arow[s] * ep[e];
  }
  out[(size_t)b * E2D + e] = acc;
}

__global__ __launch_bounds__(256) void k_concat_x(const float* __restrict__ emb,
    const float* __restrict__ wgt, float* __restrict__ x) {
  int b = blockIdx.x;
  for (int i = threadIdx.x; i < EMBD + E2D; i += 256)
    x[(size_t)b*(EMBD+E2D) + i] = (i < EMBD) ? emb[(size_t)b*EMBD + i]
                                             : wgt[(size_t)b*E2D + i - EMBD];
}

__global__ __launch_bounds__(256) void k_concat_state(const float* __restrict__ hnew,
    const float* __restrict__ wgt, float* __restrict__ st) {
  int b = blockIdx.x;
  for (int i = threadIdx.x; i < DECD + E2D; i += 256)
    st[(size_t)b*(DECD+E2D) + i] = (i < DECD) ? hnew[(size_t)b*DECD + i]
                                              : wgt[(size_t)b*E2D + i - DECD];
}

// C[128][N] = A[128][K] @ B[N][K]^T + bias ; tiles: 128x64, thread 8x4, K-chunk 16
__global__ __launch_bounds__(256) void gemm_abt(
    const float* __restrict__ A, int lda,
    const float* __restrict__ Bm, int ldb,
    const float* __restrict__ bias,
    float* __restrict__ C, int ldc,
    int N, int K) {
  __shared__ float As[16][132];
  __shared__ float Bs[16][68];
  int tid = threadIdx.x;
  int nb = blockIdx.x * 64;
  int m0 = (tid & 15) * 8;
  int n0 = (tid >> 4) * 4;
  float acc[8][4];
  #pragma unroll
  for (int i = 0; i < 8; ++i)
    #pragma unroll
    for (int j = 0; j < 4; ++j) acc[i][j] = 0.f;
  int lm = tid >> 2;
  int lk = (tid & 3) * 4;
  for (int k0 = 0; k0 < K; k0 += 16) {
    float4 av0 = *(const float4*)&A[(size_t)lm * lda + k0 + lk];
    float4 av1 = *(const float4*)&A[(size_t)(lm + 64) * lda + k0 + lk];
    int gn = nb + lm;
    float4 bv = make_float4(0.f, 0.f, 0.f, 0.f);
    if (gn < N) bv = *(const float4*)&Bm[(size_t)gn * ldb + k0 + lk];
    As[lk+0][lm]    = av0.x; As[lk+1][lm]    = av0.y; As[lk+2][lm]    = av0.z; As[lk+3][lm]    = av0.w;
    As[lk+0][lm+64] = av1.x; As[lk+1][lm+64] = av1.y; As[lk+2][lm+64] = av1.z; As[lk+3][lm+64] = av1.w;
    Bs[lk+0][lm] = bv.x; Bs[lk+1][lm] = bv.y; Bs[lk+2][lm] = bv.z; Bs[lk+3][lm] = bv.w;
    __syncthreads();
    #pragma unroll
    for (int kk = 0; kk < 16; ++kk) {
      float4 a0 = *(const float4*)&As[kk][m0];
      float4 a1 = *(const float4*)&As[kk][m0 + 4];
      float4 bb = *(const float4*)&Bs[kk][n0];
      float am[8] = {a0.x, a0.y, a0.z, a0.w, a1.x, a1.y, a1.z, a1.w};
      float bn[4] = {bb.x, bb.y, bb.z, bb.w};
      #pragma unroll
      for (int i = 0; i < 8; ++i)
        #pragma unroll
        for (int j = 0; j < 4; ++j) acc[i][j] += am[i] * bn[j];
    }
    __syncthreads();
  }
  #pragma unroll
  for (int i = 0; i < 8; ++i) {
    int m = m0 + i;
    #pragma unroll
    for (int j = 0; j < 4; ++j) {
      int gn = nb + n0 + j;
      if (gn < N) C[(size_t)m * ldc + gn] = acc[i][j] + (bias ? bias[gn] : 0.f);
    }
  }
}

__global__ __launch_bounds__(256) void k_gru(const float* __restrict__ gx,
    const float* __restrict__ gh, const float* __restrict__ hidden,
    float* __restrict__ hnew) {
  int b = blockIdx.x, tid = threadIdx.x;
  #pragma unroll
  for (int q = 0; q < 2; ++q) {
    int d = tid + q * 256;
    size_t o = (size_t)b * 1536;
    float xr = gx[o + d],        hr = gh[o + d];
    float xz = gx[o + 512 + d],  hz = gh[o + 512 + d];
    float xn = gx[o + 1024 + d], hn = gh[o + 1024 + d];
    float r = 1.f / (1.f + expf(-(xr + hr)));
    float z = 1.f / (1.f + expf(-(xz + hz)));
    float n = tanhf(xn + r * hn);
    hnew[(size_t)b * DECD + d] = (1.f - z) * n + z * hidden[(size_t)b * DECD + d];
  }
}

__global__ __launch_bounds__(256) void k_pgen(const float* __restrict__ wgt,
    const float* __restrict__ emb, const float* __restrict__ gW,
    const float* __restrict__ gb, float* __restrict__ pg) {
  int b = blockIdx.x, tid = threadIdx.x;
  __shared__ float sm[4];
  float s = 0.f;
  for (int k = tid; k < E2D + EMBD; k += 256)
    s += gW[k] * ((k < E2D) ? wgt[(size_t)b*E2D + k] : emb[(size_t)b*EMBD + k - E2D]);
  #pragma unroll
  for (int off = 32; off > 0; off >>= 1) s += __shfl_down(s, off, 64);
  int lane = tid & 63, wid = tid >> 6;
  if (lane == 0) sm[wid] = s;
  __syncthreads();
  if (tid == 0) {
    float t = sm[0] + sm[1] + sm[2] + sm[3] + gb[0];
    pg[b] = 1.f / (1.f + expf(-t));
  }
}

__global__ __launch_bounds__(256) void k_vocab(float* __restrict__ dist,
    const float* __restrict__ pg) {
  int b = blockIdx.x, tid = threadIdx.x;
  float* row = dist + (size_t)b * VV;
  __shared__ float sm[4];
  float m = -INFINITY;
  for (int i = tid; i < VV; i += 256) m = fmaxf(m, row[i]);
  #pragma unroll
  for (int off = 32; off > 0; off >>= 1) m = fmaxf(m, __shfl_down(m, off, 64));
  int lane = tid & 63, wid = tid >> 6;
  if (lane == 0) sm[wid] = m;
  __syncthreads();
  m = fmaxf(fmaxf(sm[0], sm[1]), fmaxf(sm[2], sm[3]));
  __syncthreads();
  float s = 0.f;
  for (int i = tid; i < VV; i += 256) s += expf(row[i] - m);
  #pragma unroll
  for (int off = 32; off > 0; off >>= 1) s += __shfl_down(s, off, 64);
  if (lane == 0) sm[wid] = s;
  __syncthreads();
  s = sm[0] + sm[1] + sm[2] + sm[3];
  float scale = pg[b] / s;
  for (int i = tid; i < VV; i += 256) row[i] = expf(row[i] - m) * scale;
}

__global__ __launch_bounds__(256) void k_scatter(float* __restrict__ dist,
    const float* __restrict__ ad, const float* __restrict__ pg,
    const int* __restrict__ src1) {
  int b = blockIdx.x, tid = threadIdx.x;
  if (tid < S1D) {
    float val = (1.f - pg[b]) * ad[(size_t)b * S1D + tid];
    int tok = src1[(size_t)tid * BB + b];
    atomicAdd(&dist[(size_t)b * VV + tok], val);
  }
}

extern "C" void kernel_launch(void* const* d_in, const int* in_sizes, int n_in,
                              void* d_out, int out_size, void* d_ws, size_t ws_size,
                              hipStream_t stream) {
  (void)in_sizes; (void)n_in; (void)out_size; (void)ws_size;
  const int*   input  = (const int*)d_in[0];
  const float* hidden = (const float*)d_in[1];
  const int*   src1   = (const int*)d_in[2];
  const float* enc1   = (const float*)d_in[3];
  const int*   mask1  = (const int*)d_in[4];
  const int*   triple = (const int*)d_in[5];
  const float* enc2   = (const float*)d_in[6];
  const int*   mask2  = (const int*)d_in[7];
  const float* embedding = (const float*)d_in[8];
  const float* attn_W = (const float*)d_in[9];
  const float* attn_b = (const float*)d_in[10];
  const float* attn_v = (const float*)d_in[11];
  const float* copy_W = (const float*)d_in[12];
  const float* copy_b = (const float*)d_in[13];
  const float* copy_v = (const float*)d_in[14];
  const float* gru_Wih = (const float*)d_in[15];
  const float* gru_Whh = (const float*)d_in[16];
  const float* gru_bih = (const float*)d_in[17];
  const float* gru_bhh = (const float*)d_in[18];
  const float* fc_W   = (const float*)d_in[19];
  const float* fc_b   = (const float*)d_in[20];
  const float* gate_W = (const float*)d_in[21];
  const float* gate_b = (const float*)d_in[22];

  float* ws   = (float*)d_ws;
  float* emb  = ws + O_EMB;
  float* hWa  = ws + O_HWA;
  float* scJ  = ws + O_SCJ;
  float* wgt  = ws + O_WGT;
  float* x    = ws + O_X;
  float* gx   = ws + O_GX;
  float* gh   = ws + O_GH;
  float* st   = ws + O_ST;
  float* hWc  = ws + O_HWC;
  float* scC  = ws + O_SCC;
  float* pg   = ws + O_PG;

  float* out  = (float*)d_out;
  float* hnew = out + (size_t)BB * VV;

  k_emb<<<BB, 256, 0, stream>>>(input, embedding, emb);
  k_partial<<<dim3(2, BB), 256, 0, stream>>>(hidden, attn_W, attn_b, hWa);
  k_scores<<<SJD * 8, 256, 0, stream>>>(enc1, enc2, attn_W + DECD * DECD, hWa, attn_v, scJ, SJD);
  k_softmax_s<<<BB, 256, 0, stream>>>(scJ, SJD, mask1, mask2, 0);
  k_weighted<<<dim3(BB, 4), 256, 0, stream>>>(enc1, enc2, scJ, wgt);
  k_concat_x<<<BB, 256, 0, stream>>>(emb, wgt, x);
  gemm_abt<<<1536 / 64, 256, 0, stream>>>(x, 1280, gru_Wih, 1280, gru_bih, gx, 1536, 1536, 1280);
  gemm_abt<<<1536 / 64, 256, 0, stream>>>(hidden, 512, gru_Whh, 512, gru_bhh, gh, 1536, 1536, 512);
  k_gru<<<BB, 256, 0, stream>>>(gx, gh, hidden, hnew);
  k_concat_state<<<BB, 256, 0, stream>>>(hnew, wgt, st);
  gemm_abt<<<(VV + 63) / 64, 256, 0, stream>>>(st, 1536, fc_W, 1536, fc_b, out, VV, VV, 1536);
  k_pgen<<<BB, 256, 0, stream>>>(wgt, emb, gate_W, gate_b, pg);
  k_partial<<<dim3(2, BB), 256, 0, stream>>>(hnew, copy_W, copy_b, hWc);
  k_scores<<<S1D * 8, 256, 0, stream>>>(enc1, enc1, copy_W + DECD * DECD, hWc, copy_v, scC, S1D);
  k_softmax_s<<<BB, 256, 0, stream>>>(scC, S1D, mask1, triple, 1);
  k_vocab<<<BB, 256, 0, stream>>>(out, pg);
  k_scatter<<<BB, 256, 0, stream>>>(out, scC, pg, src1);
}

// Round 2
// 978.196 us; speedup vs baseline: 2.4521x; 2.4521x over previous
//
#include <hip/hip_runtime.h>
#include <math.h>

#define BB   128
#define DECD 512
#define E2D  1024
#define EMBD 256
#define S1D  200
#define S2D  200
#define SJD  400
#define VV   50000
#define NEGV (-1e10f)

typedef unsigned short u16;
typedef __bf16 bf16x8 __attribute__((ext_vector_type(8)));
typedef float f32x4 __attribute__((ext_vector_type(4)));
typedef u16 u16x8 __attribute__((ext_vector_type(8)));

__device__ __forceinline__ u16 f2bf(float x) {
  unsigned u = __float_as_uint(x);
  unsigned r = (u + 0x7fffu + ((u >> 16) & 1u)) >> 16;
  return (u16)r;
}
__device__ __forceinline__ float bf2f(u16 h) {
  return __uint_as_float(((unsigned)h) << 16);
}

typedef const __attribute__((address_space(1))) void* gas_t;
typedef __attribute__((address_space(3))) void* las_t;
__device__ __forceinline__ void async_copy16(const u16* g, u16* l) {
  __builtin_amdgcn_global_load_lds((gas_t)g, (las_t)l, 16, 0, 0);
}

// ---------------- conversion kernels ----------------
__global__ __launch_bounds__(256) void k_cvt(const float* __restrict__ src,
    u16* __restrict__ dst, int n8) {
  int i = blockIdx.x * 256 + threadIdx.x;
  if (i >= n8) return;
  const float4 f0 = *(const float4*)(src + (size_t)i * 8);
  const float4 f1 = *(const float4*)(src + (size_t)i * 8 + 4);
  u16x8 o;
  o[0] = f2bf(f0.x); o[1] = f2bf(f0.y); o[2] = f2bf(f0.z); o[3] = f2bf(f0.w);
  o[4] = f2bf(f1.x); o[5] = f2bf(f1.y); o[6] = f2bf(f1.z); o[7] = f2bf(f1.w);
  *(u16x8*)(dst + (size_t)i * 8) = o;
}

// Wt[n][k] = bf16( W[512+k][n] ), n in [0,512), k in [0,1024). grid (32,16), 256 thr
__global__ __launch_bounds__(256) void k_wt(const float* __restrict__ W,
    u16* __restrict__ Wt) {
  __shared__ float t[32][33];
  int bk = blockIdx.x, bn = blockIdx.y;
  int tx = threadIdx.x & 31, ty = threadIdx.x >> 5;   // ty 0..7
  #pragma unroll
  for (int r = 0; r < 4; ++r) {
    int k = bk * 32 + ty + r * 8;
    t[ty + r * 8][tx] = W[(size_t)(512 + k) * 512 + bn * 32 + tx];
  }
  __syncthreads();
  #pragma unroll
  for (int r = 0; r < 4; ++r) {
    int n = bn * 32 + ty + r * 8;
    Wt[(size_t)n * 1024 + bk * 32 + tx] = f2bf(t[tx][ty + r * 8]);
  }
}

// ---------------- fused MFMA GEMM + energy epilogue ----------------
// part[blk_n][m] = sum_{d in n-block} tanh( (A@Wt^T)[m][d] + hW[b][d] ) * v[d]
// A: [M][1024] bf16, one s per 128 rows (b = row & 127). Wt: [512][1024] bf16.
__global__ __launch_bounds__(256) void gemm_energy(
    const u16* __restrict__ A, const u16* __restrict__ Bt,
    const float* __restrict__ hW, const float* __restrict__ v,
    float* __restrict__ part, int M) {
  __shared__ u16 As[128 * 32];
  __shared__ u16 Bs[128 * 32];
  __shared__ float sbuf[128][2];
  int tid = threadIdx.x;
  int wid = tid >> 6, lane = tid & 63;
  int wr = wid >> 1, wc = wid & 1;
  int m0 = blockIdx.x * 128;
  int n0 = blockIdx.y * 128;

  // staging address precompute (source pre-swizzle: chunk c' = c ^ ((r>>1)&3))
  int idx0 = tid, idx1 = tid + 256;
  int rA0 = idx0 >> 2, cA0 = (idx0 & 3) ^ ((rA0 >> 1) & 3);
  int rA1 = idx1 >> 2, cA1 = (idx1 & 3) ^ ((rA1 >> 1) & 3);
  const u16* gA0 = A + (size_t)(m0 + rA0) * 1024 + cA0 * 8;
  const u16* gA1 = A + (size_t)(m0 + rA1) * 1024 + cA1 * 8;
  const u16* gB0 = Bt + (size_t)(n0 + rA0) * 1024 + cA0 * 8;
  const u16* gB1 = Bt + (size_t)(n0 + rA1) * 1024 + cA1 * 8;
  u16* lA0 = As + wid * 512;          // (wid*64 lanes)*8 u16
  u16* lA1 = As + 2048 + wid * 512;
  u16* lB0 = Bs + wid * 512;
  u16* lB1 = Bs + 2048 + wid * 512;

  // fragment LDS byte offsets (constant across K steps)
  int q = lane >> 4, cl = lane & 15;
  int aoff[4], boff[4];
  #pragma unroll
  for (int mi = 0; mi < 4; ++mi) {
    int row = wr * 64 + mi * 16 + cl;
    aoff[mi] = row * 64 + ((q ^ ((row >> 1) & 3)) * 16);
  }
  #pragma unroll
  for (int nj = 0; nj < 4; ++nj) {
    int rn = wc * 64 + nj * 16 + cl;
    boff[nj] = rn * 64 + ((q ^ ((rn >> 1) & 3)) * 16);
  }

  f32x4 acc[4][4];
  #pragma unroll
  for (int mi = 0; mi < 4; ++mi)
    #pragma unroll
    for (int nj = 0; nj < 4; ++nj) {
      f32x4 z = {0.f, 0.f, 0.f, 0.f};
      acc[mi][nj] = z;
    }

  for (int k0 = 0; k0 < 1024; k0 += 32) {
    async_copy16(gA0 + k0, lA0);
    async_copy16(gA1 + k0, lA1);
    async_copy16(gB0 + k0, lB0);
    async_copy16(gB1 + k0, lB1);
    __syncthreads();
    bf16x8 af[4], bg[4];
    #pragma unroll
    for (int mi = 0; mi < 4; ++mi)
      af[mi] = *(const bf16x8*)((const char*)As + aoff[mi]);
    #pragma unroll
    for (int nj = 0; nj < 4; ++nj)
      bg[nj] = *(const bf16x8*)((const char*)Bs + boff[nj]);
    #pragma unroll
    for (int mi = 0; mi < 4; ++mi)
      #pragma unroll
      for (int nj = 0; nj < 4; ++nj)
        acc[mi][nj] = __builtin_amdgcn_mfma_f32_16x16x32_bf16(af[mi], bg[nj], acc[mi][nj], 0, 0, 0);
    __syncthreads();
  }

  // epilogue: energy = tanh(acc + hW[b][d]) * v[d]; reduce over d
  #pragma unroll
  for (int mi = 0; mi < 4; ++mi) {
    #pragma unroll
    for (int j = 0; j < 4; ++j) {
      int b = wr * 64 + mi * 16 + q * 4 + j;
      float s = 0.f;
      #pragma unroll
      for (int nj = 0; nj < 4; ++nj) {
        int d = n0 + wc * 64 + nj * 16 + cl;
        s += tanhf(acc[mi][nj][j] + hW[(size_t)b * DECD + d]) * v[d];
      }
      s += __shfl_xor(s, 1, 64);
      s += __shfl_xor(s, 2, 64);
      s += __shfl_xor(s, 4, 64);
      s += __shfl_xor(s, 8, 64);
      if (cl == 0) sbuf[b][wc] = s;
    }
  }
  __syncthreads();
  if (tid < 128)
    part[(size_t)blockIdx.y * M + m0 + tid] = sbuf[tid][0] + sbuf[tid][1];
}

// scores[b][s] = sum of 4 n-block partials
__global__ __launch_bounds__(256) void k_sum4(const float* __restrict__ part,
    float* __restrict__ sc, int M, int S) {
  int m = blockIdx.x * 256 + threadIdx.x;
  if (m >= M) return;
  int b = m & 127, s = m >> 7;
  sc[(size_t)b * S + s] = part[m] + part[M + m] + part[2 * M + m] + part[3 * M + m];
}

// ---------------- small kernels ----------------
__global__ __launch_bounds__(256) void k_emb(const int* __restrict__ inp,
    const float* __restrict__ table, float* __restrict__ emb) {
  int b = blockIdx.x;
  int t = threadIdx.x;
  emb[(size_t)b * EMBD + t] = table[(size_t)inp[b] * EMBD + t];
}

__global__ __launch_bounds__(256) void k_partial(const float* __restrict__ h,
    const float* __restrict__ W, const float* __restrict__ bias,
    float* __restrict__ out) {
  int b = blockIdx.y;
  int d = blockIdx.x * 256 + threadIdx.x;
  const float* hr = h + (size_t)b * DECD;
  float acc = bias[d];
  #pragma unroll 8
  for (int k = 0; k < DECD; ++k) acc += hr[k] * W[(size_t)k * DECD + d];
  out[(size_t)b * DECD + d] = acc;
}

__global__ __launch_bounds__(256) void k_softmax_s(float* __restrict__ sc, int S,
    const int* __restrict__ m1, const int* __restrict__ m2, int mode) {
  int b = blockIdx.x, tid = threadIdx.x;
  __shared__ float sm[4];
  int s0 = tid, s2 = tid + 256;
  float a0 = -INFINITY, a1 = -INFINITY;
  if (s0 < S) {
    int msk = (mode == 0) ? ((s0 < S1D) ? m1[b * S1D + s0] : m2[b * S2D + (s0 - S1D)])
                          : (m1[b * S1D + s0] * m2[b * S1D + s0]);
    a0 = msk ? sc[(size_t)b * S + s0] : NEGV;
  }
  if (s2 < S) {
    int msk = (mode == 0) ? ((s2 < S1D) ? m1[b * S1D + s2] : m2[b * S2D + (s2 - S1D)])
                          : (m1[b * S1D + s2] * m2[b * S1D + s2]);
    a1 = msk ? sc[(size_t)b * S + s2] : NEGV;
  }
  float vmax = fmaxf(a0, a1);
  #pragma unroll
  for (int off = 32; off > 0; off >>= 1) vmax = fmaxf(vmax, __shfl_down(vmax, off, 64));
  int lane = tid & 63, wid = tid >> 6;
  if (lane == 0) sm[wid] = vmax;
  __syncthreads();
  vmax = fmaxf(fmaxf(sm[0], sm[1]), fmaxf(sm[2], sm[3]));
  __syncthreads();
  float lsum = 0.f;
  if (s0 < S) lsum += expf(a0 - vmax);
  if (s2 < S) lsum += expf(a1 - vmax);
  #pragma unroll
  for (int off = 32; off > 0; off >>= 1) lsum += __shfl_down(lsum, off, 64);
  if (lane == 0) sm[wid] = lsum;
  __syncthreads();
  float inv = 1.0f / (sm[0] + sm[1] + sm[2] + sm[3]);
  if (s0 < S) sc[(size_t)b * S + s0] = expf(a0 - vmax) * inv;
  if (s2 < S) sc[(size_t)b * S + s2] = expf(a1 - vmax) * inv;
}

// weighted partials over s-chunks of 100; grid (128, 2, 4)
__global__ __launch_bounds__(256) void k_wpart(const u16* __restrict__ A,
    const float* __restrict__ a, float* __restrict__ wp) {
  int b = blockIdx.x;
  int e2 = blockIdx.y * 256 + threadIdx.x;   // pair index [0,512)
  int scn = blockIdx.z;
  const float* arow = a + (size_t)b * SJD;
  float acc0 = 0.f, acc1 = 0.f;
  #pragma unroll 4
  for (int s = scn * 100; s < scn * 100 + 100; ++s) {
    unsigned u = *(const unsigned*)(A + ((size_t)s * BB + b) * E2D + e2 * 2);
    float w = arow[s];
    acc0 += w * bf2f((u16)(u & 0xffff));
    acc1 += w * bf2f((u16)(u >> 16));
  }
  float* dst = wp + ((size_t)scn * BB + b) * E2D + e2 * 2;
  dst[0] = acc0;
  dst[1] = acc1;
}

__global__ __launch_bounds__(256) void k_wsum(const float* __restrict__ wp,
    float* __restrict__ wgt) {
  int i = blockIdx.x * 256 + threadIdx.x;   // 131072 elements
  const int N = BB * E2D;
  wgt[i] = wp[i] + wp[N + i] + wp[2 * N + i] + wp[3 * N + i];
}

__global__ __launch_bounds__(256) void k_concat_x(const float* __restrict__ emb,
    const float* __restrict__ wgt, float* __restrict__ x) {
  int b = blockIdx.x;
  for (int i = threadIdx.x; i < EMBD + E2D; i += 256)
    x[(size_t)b * (EMBD + E2D) + i] = (i < EMBD) ? emb[(size_t)b * EMBD + i]
                                                 : wgt[(size_t)b * E2D + i - EMBD];
}

__global__ __launch_bounds__(256) void k_concat_state(const float* __restrict__ hnew,
    const float* __restrict__ wgt, float* __restrict__ st) {
  int b = blockIdx.x;
  for (int i = threadIdx.x; i < DECD + E2D; i += 256)
    st[(size_t)b * (DECD + E2D) + i] = (i < DECD) ? hnew[(size_t)b * DECD + i]
                                                  : wgt[(size_t)b * E2D + i - DECD];
}

// C[128][N] = A[128][K] @ B[N][K]^T + bias
__global__ __launch_bounds__(256) void gemm_abt(
    const float* __restrict__ A, int lda,
    const float* __restrict__ Bm, int ldb,
    const float* __restrict__ bias,
    float* __restrict__ C, int ldc,
    int N, int K) {
  __shared__ float As[16][132];
  __shared__ float Bs[16][68];
  int tid = threadIdx.x;
  int nb = blockIdx.x * 64;
  int m0 = (tid & 15) * 8;
  int n0 = (tid >> 4) * 4;
  float acc[8][4];
  #pragma unroll
  for (int i = 0; i < 8; ++i)
    #pragma unroll
    for (int j = 0; j < 4; ++j) acc[i][j] = 0.f;
  int lm = tid >> 2;
  int lk = (tid & 3) * 4;
  for (int k0 = 0; k0 < K; k0 += 16) {
    float4 av0 = *(const float4*)&A[(size_t)lm * lda + k0 + lk];
    float4 av1 = *(const float4*)&A[(size_t)(lm + 64) * lda + k0 + lk];
    int gn = nb + lm;
    float4 bv = make_float4(0.f, 0.f, 0.f, 0.f);
    if (gn < N) bv = *(const float4*)&Bm[(size_t)gn * ldb + k0 + lk];
    As[lk + 0][lm] = av0.x; As[lk + 1][lm] = av0.y; As[lk + 2][lm] = av0.z; As[lk + 3][lm] = av0.w;
    As[lk + 0][lm + 64] = av1.x; As[lk + 1][lm + 64] = av1.y; As[lk + 2][lm + 64] = av1.z; As[lk + 3][lm + 64] = av1.w;
    Bs[lk + 0][lm] = bv.x; Bs[lk + 1][lm] = bv.y; Bs[lk + 2][lm] = bv.z; Bs[lk + 3][lm] = bv.w;
    __syncthreads();
    #pragma unroll
    for (int kk = 0; kk < 16; ++kk) {
      float4 a0 = *(const float4*)&As[kk][m0];
      float4 a1 = *(const float4*)&As[kk][m0 + 4];
      float4 bb = *(const float4*)&Bs[kk][n0];
      float am[8] = {a0.x, a0.y, a0.z, a0.w, a1.x, a1.y, a1.z, a1.w};
      float bn[4] = {bb.x, bb.y, bb.z, bb.w};
      #pragma unroll
      for (int i = 0; i < 8; ++i)
        #pragma unroll
        for (int j = 0; j < 4; ++j) acc[i][j] += am[i] * bn[j];
    }
    __syncthreads();
  }
  #pragma unroll
  for (int i = 0; i < 8; ++i) {
    int m = m0 + i;
    #pragma unroll
    for (int j = 0; j < 4; ++j) {
      int gn = nb + n0 + j;
      if (gn < N) C[(size_t)m * ldc + gn] = acc[i][j] + (bias ? bias[gn] : 0.f);
    }
  }
}

__global__ __launch_bounds__(256) void k_gru(const float* __restrict__ gx,
    const float* __restrict__ gh, const float* __restrict__ hidden,
    float* __restrict__ hnew) {
  int b = blockIdx.x, tid = threadIdx.x;
  #pragma unroll
  for (int qq = 0; qq < 2; ++qq) {
    int d = tid + qq * 256;
    size_t o = (size_t)b * 1536;
    float xr = gx[o + d],        hr = gh[o + d];
    float xz = gx[o + 512 + d],  hz = gh[o + 512 + d];
    float xn = gx[o + 1024 + d], hn = gh[o + 1024 + d];
    float r = 1.f / (1.f + expf(-(xr + hr)));
    float z = 1.f / (1.f + expf(-(xz + hz)));
    float n = tanhf(xn + r * hn);
    hnew[(size_t)b * DECD + d] = (1.f - z) * n + z * hidden[(size_t)b * DECD + d];
  }
}

__global__ __launch_bounds__(256) void k_pgen(const float* __restrict__ wgt,
    const float* __restrict__ emb, const float* __restrict__ gW,
    const float* __restrict__ gb, float* __restrict__ pg) {
  int b = blockIdx.x, tid = threadIdx.x;
  __shared__ float sm[4];
  float s = 0.f;
  for (int k = tid; k < E2D + EMBD; k += 256)
    s += gW[k] * ((k < E2D) ? wgt[(size_t)b * E2D + k] : emb[(size_t)b * EMBD + k - E2D]);
  #pragma unroll
  for (int off = 32; off > 0; off >>= 1) s += __shfl_down(s, off, 64);
  int lane = tid & 63, wid = tid >> 6;
  if (lane == 0) sm[wid] = s;
  __syncthreads();
  if (tid == 0) {
    float t = sm[0] + sm[1] + sm[2] + sm[3] + gb[0];
    pg[b] = 1.f / (1.f + expf(-t));
  }
}

__global__ __launch_bounds__(256) void k_vocab(float* __restrict__ dist,
    const float* __restrict__ pg) {
  int b = blockIdx.x, tid = threadIdx.x;
  float* row = dist + (size_t)b * VV;
  __shared__ float sm[4];
  float m = -INFINITY;
  for (int i = tid; i < VV; i += 256) m = fmaxf(m, row[i]);
  #pragma unroll
  for (int off = 32; off > 0; off >>= 1) m = fmaxf(m, __shfl_down(m, off, 64));
  int lane = tid & 63, wid = tid >> 6;
  if (lane == 0) sm[wid] = m;
  __syncthreads();
  m = fmaxf(fmaxf(sm[0], sm[1]), fmaxf(sm[2], sm[3]));
  __syncthreads();
  float s = 0.f;
  for (int i = tid; i < VV; i += 256) s += expf(row[i] - m);
  #pragma unroll
  for (int off = 32; off > 0; off >>= 1) s += __shfl_down(s, off, 64);
  if (lane == 0) sm[wid] = s;
  __syncthreads();
  s = sm[0] + sm[1] + sm[2] + sm[3];
  float scale = pg[b] / s;
  for (int i = tid; i < VV; i += 256) row[i] = expf(row[i] - m) * scale;
}

__global__ __launch_bounds__(256) void k_scatter(float* __restrict__ dist,
    const float* __restrict__ ad, const float* __restrict__ pg,
    const int* __restrict__ src1) {
  int b = blockIdx.x, tid = threadIdx.x;
  if (tid < S1D) {
    float val = (1.f - pg[b]) * ad[(size_t)b * S1D + tid];
    int tok = src1[(size_t)tid * BB + b];
    atomicAdd(&dist[(size_t)b * VV + tok], val);
  }
}

extern "C" void kernel_launch(void* const* d_in, const int* in_sizes, int n_in,
                              void* d_out, int out_size, void* d_ws, size_t ws_size,
                              hipStream_t stream) {
  (void)in_sizes; (void)n_in; (void)out_size; (void)ws_size;
  const int*   input  = (const int*)d_in[0];
  const float* hidden = (const float*)d_in[1];
  const int*   src1   = (const int*)d_in[2];
  const float* enc1   = (const float*)d_in[3];
  const int*   mask1  = (const int*)d_in[4];
  const int*   triple = (const int*)d_in[5];
  const float* enc2   = (const float*)d_in[6];
  const int*   mask2  = (const int*)d_in[7];
  const float* embedding = (const float*)d_in[8];
  const float* attn_W = (const float*)d_in[9];
  const float* attn_b = (const float*)d_in[10];
  const float* attn_v = (const float*)d_in[11];
  const float* copy_W = (const float*)d_in[12];
  const float* copy_b = (const float*)d_in[13];
  const float* copy_v = (const float*)d_in[14];
  const float* gru_Wih = (const float*)d_in[15];
  const float* gru_Whh = (const float*)d_in[16];
  const float* gru_bih = (const float*)d_in[17];
  const float* gru_bhh = (const float*)d_in[18];
  const float* fc_W   = (const float*)d_in[19];
  const float* fc_b   = (const float*)d_in[20];
  const float* gate_W = (const float*)d_in[21];
  const float* gate_b = (const float*)d_in[22];

  char* w = (char*)d_ws;
  u16* A_bf = (u16*)w;                w += (size_t)51200 * 1024 * 2;
  u16* Wt_a = (u16*)w;                w += (size_t)512 * 1024 * 2;
  u16* Wt_c = (u16*)w;                w += (size_t)512 * 1024 * 2;
  float* partJ = (float*)w;           w += (size_t)4 * 51200 * 4;
  float* partC = (float*)w;           w += (size_t)4 * 25600 * 4;
  float* emb  = (float*)w;            w += (size_t)BB * EMBD * 4;
  float* hWa  = (float*)w;            w += (size_t)BB * DECD * 4;
  float* hWc  = (float*)w;            w += (size_t)BB * DECD * 4;
  float* scJ  = (float*)w;            w += (size_t)BB * SJD * 4;
  float* scC  = (float*)w;            w += (size_t)BB * S1D * 4;
  float* wgt  = (float*)w;            w += (size_t)BB * E2D * 4;
  float* wpart = (float*)w;           w += (size_t)4 * BB * E2D * 4;
  float* x    = (float*)w;            w += (size_t)BB * 1280 * 4;
  float* gx   = (float*)w;            w += (size_t)BB * 1536 * 4;
  float* gh   = (float*)w;            w += (size_t)BB * 1536 * 4;
  float* st   = (float*)w;            w += (size_t)BB * 1536 * 4;
  float* pg   = (float*)w;            w += 512;

  float* out  = (float*)d_out;
  float* hnew = out + (size_t)BB * VV;

  // conversions
  k_cvt<<<12800, 256, 0, stream>>>(enc1, A_bf, 25600 * 1024 / 8);
  k_cvt<<<12800, 256, 0, stream>>>(enc2, A_bf + (size_t)25600 * 1024, 25600 * 1024 / 8);
  k_wt<<<dim3(32, 16), 256, 0, stream>>>(attn_W, Wt_a);
  k_wt<<<dim3(32, 16), 256, 0, stream>>>(copy_W, Wt_c);

  k_emb<<<BB, 256, 0, stream>>>(input, embedding, emb);
  k_partial<<<dim3(2, BB), 256, 0, stream>>>(hidden, attn_W, attn_b, hWa);

  // joint attention scores
  gemm_energy<<<dim3(400, 4), 256, 0, stream>>>(A_bf, Wt_a, hWa, attn_v, partJ, 51200);
  k_sum4<<<200, 256, 0, stream>>>(partJ, scJ, 51200, SJD);
  k_softmax_s<<<BB, 256, 0, stream>>>(scJ, SJD, mask1, mask2, 0);

  // weighted context
  k_wpart<<<dim3(BB, 2, 4), 256, 0, stream>>>(A_bf, scJ, wpart);
  k_wsum<<<512, 256, 0, stream>>>(wpart, wgt);

  // GRU
  k_concat_x<<<BB, 256, 0, stream>>>(emb, wgt, x);
  gemm_abt<<<1536 / 64, 256, 0, stream>>>(x, 1280, gru_Wih, 1280, gru_bih, gx, 1536, 1536, 1280);
  gemm_abt<<<1536 / 64, 256, 0, stream>>>(hidden, 512, gru_Whh, 512, gru_bhh, gh, 1536, 1536, 512);
  k_gru<<<BB, 256, 0, stream>>>(gx, gh, hidden, hnew);

  // vocab logits
  k_concat_state<<<BB, 256, 0, stream>>>(hnew, wgt, st);
  gemm_abt<<<(VV + 63) / 64, 256, 0, stream>>>(st, 1536, fc_W, 1536, fc_b, out, VV, VV, 1536);

  // copy path
  k_pgen<<<BB, 256, 0, stream>>>(wgt, emb, gate_W, gate_b, pg);
  k_partial<<<dim3(2, BB), 256, 0, stream>>>(hnew, copy_W, copy_b, hWc);
  gemm_energy<<<dim3(200, 4), 256, 0, stream>>>(A_bf, Wt_c, hWc, copy_v, partC, 25600);
  k_sum4<<<100, 256, 0, stream>>>(partC, scC, 25600, S1D);
  k_softmax_s<<<BB, 256, 0, stream>>>(scC, S1D, mask1, triple, 1);

  // final distribution
  k_vocab<<<BB, 256, 0, stream>>>(out, pg);
  k_scatter<<<BB, 256, 0, stream>>>(out, scC, pg, src1);
}

// Round 3
// 745.155 us; speedup vs baseline: 3.2190x; 1.3127x over previous
//
#include <hip/hip_runtime.h>
#include <math.h>

#define BB   128
#define DECD 512
#define E2D  1024
#define EMBD 256
#define S1D  200
#define S2D  200
#define SJD  400
#define VV   50000
#define NEGV (-1e10f)

typedef unsigned short u16;
typedef __bf16 bf16x8 __attribute__((ext_vector_type(8)));
typedef float f32x4 __attribute__((ext_vector_type(4)));
typedef u16 u16x8 __attribute__((ext_vector_type(8)));

__device__ __forceinline__ u16 f2bf(float x) {
  unsigned u = __float_as_uint(x);
  unsigned r = (u + 0x7fffu + ((u >> 16) & 1u)) >> 16;
  return (u16)r;
}
__device__ __forceinline__ float bf2f(u16 h) {
  return __uint_as_float(((unsigned)h) << 16);
}

typedef const __attribute__((address_space(1))) void* gas_t;
typedef __attribute__((address_space(3))) void* las_t;
__device__ __forceinline__ void async_copy16(const u16* g, u16* l) {
  __builtin_amdgcn_global_load_lds((gas_t)g, (las_t)l, 16, 0, 0);
}

// ---------------- conversion kernels ----------------
__global__ __launch_bounds__(256) void k_cvt(const float* __restrict__ src,
    u16* __restrict__ dst, int n8) {
  int i = blockIdx.x * 256 + threadIdx.x;
  if (i >= n8) return;
  const float4 f0 = *(const float4*)(src + (size_t)i * 8);
  const float4 f1 = *(const float4*)(src + (size_t)i * 8 + 4);
  u16x8 o;
  o[0] = f2bf(f0.x); o[1] = f2bf(f0.y); o[2] = f2bf(f0.z); o[3] = f2bf(f0.w);
  o[4] = f2bf(f1.x); o[5] = f2bf(f1.y); o[6] = f2bf(f1.z); o[7] = f2bf(f1.w);
  *(u16x8*)(dst + (size_t)i * 8) = o;
}

// Wt[n][k] = bf16( W[512+k][n] ), n in [0,512), k in [0,1024). grid (32,16), 256 thr
__global__ __launch_bounds__(256) void k_wt(const float* __restrict__ W,
    u16* __restrict__ Wt) {
  __shared__ float t[32][33];
  int bk = blockIdx.x, bn = blockIdx.y;
  int tx = threadIdx.x & 31, ty = threadIdx.x >> 5;   // ty 0..7
  #pragma unroll
  for (int r = 0; r < 4; ++r) {
    int k = bk * 32 + ty + r * 8;
    t[ty + r * 8][tx] = W[(size_t)(512 + k) * 512 + bn * 32 + tx];
  }
  __syncthreads();
  #pragma unroll
  for (int r = 0; r < 4; ++r) {
    int n = bn * 32 + ty + r * 8;
    Wt[(size_t)n * 1024 + bk * 32 + tx] = f2bf(t[tx][ty + r * 8]);
  }
}

// ---------------- fused MFMA GEMM + energy epilogue ----------------
__global__ __launch_bounds__(256) void gemm_energy(
    const u16* __restrict__ A, const u16* __restrict__ Bt,
    const float* __restrict__ hW, const float* __restrict__ v,
    float* __restrict__ part, int M) {
  __shared__ u16 As[128 * 32];
  __shared__ u16 Bs[128 * 32];
  __shared__ float sbuf[128][2];
  int tid = threadIdx.x;
  int wid = tid >> 6, lane = tid & 63;
  int wr = wid >> 1, wc = wid & 1;
  int m0 = blockIdx.x * 128;
  int n0 = blockIdx.y * 128;

  int idx0 = tid, idx1 = tid + 256;
  int rA0 = idx0 >> 2, cA0 = (idx0 & 3) ^ ((rA0 >> 1) & 3);
  int rA1 = idx1 >> 2, cA1 = (idx1 & 3) ^ ((rA1 >> 1) & 3);
  const u16* gA0 = A + (size_t)(m0 + rA0) * 1024 + cA0 * 8;
  const u16* gA1 = A + (size_t)(m0 + rA1) * 1024 + cA1 * 8;
  const u16* gB0 = Bt + (size_t)(n0 + rA0) * 1024 + cA0 * 8;
  const u16* gB1 = Bt + (size_t)(n0 + rA1) * 1024 + cA1 * 8;
  u16* lA0 = As + wid * 512;
  u16* lA1 = As + 2048 + wid * 512;
  u16* lB0 = Bs + wid * 512;
  u16* lB1 = Bs + 2048 + wid * 512;

  int q = lane >> 4, cl = lane & 15;
  int aoff[4], boff[4];
  #pragma unroll
  for (int mi = 0; mi < 4; ++mi) {
    int row = wr * 64 + mi * 16 + cl;
    aoff[mi] = row * 64 + ((q ^ ((row >> 1) & 3)) * 16);
  }
  #pragma unroll
  for (int nj = 0; nj < 4; ++nj) {
    int rn = wc * 64 + nj * 16 + cl;
    boff[nj] = rn * 64 + ((q ^ ((rn >> 1) & 3)) * 16);
  }

  f32x4 acc[4][4];
  #pragma unroll
  for (int mi = 0; mi < 4; ++mi)
    #pragma unroll
    for (int nj = 0; nj < 4; ++nj) {
      f32x4 z = {0.f, 0.f, 0.f, 0.f};
      acc[mi][nj] = z;
    }

  for (int k0 = 0; k0 < 1024; k0 += 32) {
    async_copy16(gA0 + k0, lA0);
    async_copy16(gA1 + k0, lA1);
    async_copy16(gB0 + k0, lB0);
    async_copy16(gB1 + k0, lB1);
    __syncthreads();
    bf16x8 af[4], bg[4];
    #pragma unroll
    for (int mi = 0; mi < 4; ++mi)
      af[mi] = *(const bf16x8*)((const char*)As + aoff[mi]);
    #pragma unroll
    for (int nj = 0; nj < 4; ++nj)
      bg[nj] = *(const bf16x8*)((const char*)Bs + boff[nj]);
    #pragma unroll
    for (int mi = 0; mi < 4; ++mi)
      #pragma unroll
      for (int nj = 0; nj < 4; ++nj)
        acc[mi][nj] = __builtin_amdgcn_mfma_f32_16x16x32_bf16(af[mi], bg[nj], acc[mi][nj], 0, 0, 0);
    __syncthreads();
  }

  #pragma unroll
  for (int mi = 0; mi < 4; ++mi) {
    #pragma unroll
    for (int j = 0; j < 4; ++j) {
      int b = wr * 64 + mi * 16 + q * 4 + j;
      float s = 0.f;
      #pragma unroll
      for (int nj = 0; nj < 4; ++nj) {
        int d = n0 + wc * 64 + nj * 16 + cl;
        s += tanhf(acc[mi][nj][j] + hW[(size_t)b * DECD + d]) * v[d];
      }
      s += __shfl_xor(s, 1, 64);
      s += __shfl_xor(s, 2, 64);
      s += __shfl_xor(s, 4, 64);
      s += __shfl_xor(s, 8, 64);
      if (cl == 0) sbuf[b][wc] = s;
    }
  }
  __syncthreads();
  if (tid < 128)
    part[(size_t)blockIdx.y * M + m0 + tid] = sbuf[tid][0] + sbuf[tid][1];
}

__global__ __launch_bounds__(256) void k_sum4(const float* __restrict__ part,
    float* __restrict__ sc, int M, int S) {
  int m = blockIdx.x * 256 + threadIdx.x;
  if (m >= M) return;
  int b = m & 127, s = m >> 7;
  sc[(size_t)b * S + s] = part[m] + part[M + m] + part[2 * M + m] + part[3 * M + m];
}

// ---------------- fc GEMM: C[128][N] = A_bf[128][K] @ bf16(Bf[N][K])^T + bias ----------------
// N-tile 64, 4 waves (2M x 2N), BK=32, fused fp32->bf16 conversion of B.
__global__ __launch_bounds__(256) void gemm_fc(
    const u16* __restrict__ A,      // [128][K] bf16
    const float* __restrict__ Bf,   // [N][K] fp32
    const float* __restrict__ bias, // [N]
    float* __restrict__ C,          // [128][N]
    int N, int K) {
  __shared__ u16 As[128 * 32];
  __shared__ u16 Bs[64 * 32];
  int tid = threadIdx.x;
  int wid = tid >> 6, lane = tid & 63;
  int wr = wid >> 1, wc = wid & 1;
  int n0 = blockIdx.x * 64;

  // A staging via global_load_lds (source pre-swizzled)
  int idx0 = tid, idx1 = tid + 256;
  int rA0 = idx0 >> 2, cA0 = (idx0 & 3) ^ ((rA0 >> 1) & 3);
  int rA1 = idx1 >> 2, cA1 = (idx1 & 3) ^ ((rA1 >> 1) & 3);
  const u16* gA0 = A + (size_t)rA0 * K + cA0 * 8;
  const u16* gA1 = A + (size_t)rA1 * K + cA1 * 8;
  u16* lA0 = As + wid * 512;
  u16* lA1 = As + 2048 + wid * 512;

  // B reg-staging: row rB = tid>>2, chunk cB = tid&3
  int rB = tid >> 2, cB = tid & 3;
  int gnB = n0 + rB; if (gnB >= N) gnB = N - 1;
  const float* gB = Bf + (size_t)gnB * K + cB * 8;
  int swzB = cB ^ ((rB >> 1) & 3);
  u16* lB = Bs + rB * 32 + swzB * 8;

  int q = lane >> 4, cl = lane & 15;
  int aoff[4], boff[2];
  #pragma unroll
  for (int mi = 0; mi < 4; ++mi) {
    int row = wr * 64 + mi * 16 + cl;
    aoff[mi] = row * 64 + ((q ^ ((row >> 1) & 3)) * 16);
  }
  #pragma unroll
  for (int nj = 0; nj < 2; ++nj) {
    int rn = wc * 32 + nj * 16 + cl;
    boff[nj] = rn * 64 + ((q ^ ((rn >> 1) & 3)) * 16);
  }

  f32x4 acc[4][2];
  #pragma unroll
  for (int mi = 0; mi < 4; ++mi)
    #pragma unroll
    for (int nj = 0; nj < 2; ++nj) {
      f32x4 z = {0.f, 0.f, 0.f, 0.f};
      acc[mi][nj] = z;
    }

  float4 b0 = *(const float4*)(gB);
  float4 b1 = *(const float4*)(gB + 4);

  for (int k0 = 0; k0 < K; k0 += 32) {
    // convert current B regs -> LDS (swizzled)
    u16x8 ob;
    ob[0] = f2bf(b0.x); ob[1] = f2bf(b0.y); ob[2] = f2bf(b0.z); ob[3] = f2bf(b0.w);
    ob[4] = f2bf(b1.x); ob[5] = f2bf(b1.y); ob[6] = f2bf(b1.z); ob[7] = f2bf(b1.w);
    *(u16x8*)lB = ob;
    async_copy16(gA0 + k0, lA0);
    async_copy16(gA1 + k0, lA1);
    __syncthreads();
    if (k0 + 32 < K) {            // prefetch next B while MFMA runs
      b0 = *(const float4*)(gB + k0 + 32);
      b1 = *(const float4*)(gB + k0 + 36);
    }
    bf16x8 af[4], bg[2];
    #pragma unroll
    for (int mi = 0; mi < 4; ++mi)
      af[mi] = *(const bf16x8*)((const char*)As + aoff[mi]);
    #pragma unroll
    for (int nj = 0; nj < 2; ++nj)
      bg[nj] = *(const bf16x8*)((const char*)Bs + boff[nj]);
    #pragma unroll
    for (int mi = 0; mi < 4; ++mi)
      #pragma unroll
      for (int nj = 0; nj < 2; ++nj)
        acc[mi][nj] = __builtin_amdgcn_mfma_f32_16x16x32_bf16(af[mi], bg[nj], acc[mi][nj], 0, 0, 0);
    __syncthreads();
  }

  #pragma unroll
  for (int mi = 0; mi < 4; ++mi) {
    #pragma unroll
    for (int nj = 0; nj < 2; ++nj) {
      int n = n0 + wc * 32 + nj * 16 + cl;
      if (n < N) {
        float bv = bias[n];
        #pragma unroll
        for (int j = 0; j < 4; ++j) {
          int m = wr * 64 + mi * 16 + q * 4 + j;
          C[(size_t)m * N + n] = acc[mi][nj][j] + bv;
        }
      }
    }
  }
}

// ---------------- small kernels ----------------
__global__ __launch_bounds__(256) void k_emb(const int* __restrict__ inp,
    const float* __restrict__ table, float* __restrict__ emb) {
  int b = blockIdx.x;
  int t = threadIdx.x;
  emb[(size_t)b * EMBD + t] = table[(size_t)inp[b] * EMBD + t];
}

__global__ __launch_bounds__(256) void k_partial(const float* __restrict__ h,
    const float* __restrict__ W, const float* __restrict__ bias,
    float* __restrict__ out) {
  int b = blockIdx.y;
  int d = blockIdx.x * 256 + threadIdx.x;
  const float* hr = h + (size_t)b * DECD;
  float acc = bias[d];
  #pragma unroll 8
  for (int k = 0; k < DECD; ++k) acc += hr[k] * W[(size_t)k * DECD + d];
  out[(size_t)b * DECD + d] = acc;
}

__global__ __launch_bounds__(256) void k_softmax_s(float* __restrict__ sc, int S,
    const int* __restrict__ m1, const int* __restrict__ m2, int mode) {
  int b = blockIdx.x, tid = threadIdx.x;
  __shared__ float sm[4];
  int s0 = tid, s2 = tid + 256;
  float a0 = -INFINITY, a1 = -INFINITY;
  if (s0 < S) {
    int msk = (mode == 0) ? ((s0 < S1D) ? m1[b * S1D + s0] : m2[b * S2D + (s0 - S1D)])
                          : (m1[b * S1D + s0] * m2[b * S1D + s0]);
    a0 = msk ? sc[(size_t)b * S + s0] : NEGV;
  }
  if (s2 < S) {
    int msk = (mode == 0) ? ((s2 < S1D) ? m1[b * S1D + s2] : m2[b * S2D + (s2 - S1D)])
                          : (m1[b * S1D + s2] * m2[b * S1D + s2]);
    a1 = msk ? sc[(size_t)b * S + s2] : NEGV;
  }
  float vmax = fmaxf(a0, a1);
  #pragma unroll
  for (int off = 32; off > 0; off >>= 1) vmax = fmaxf(vmax, __shfl_down(vmax, off, 64));
  int lane = tid & 63, wid = tid >> 6;
  if (lane == 0) sm[wid] = vmax;
  __syncthreads();
  vmax = fmaxf(fmaxf(sm[0], sm[1]), fmaxf(sm[2], sm[3]));
  __syncthreads();
  float lsum = 0.f;
  if (s0 < S) lsum += expf(a0 - vmax);
  if (s2 < S) lsum += expf(a1 - vmax);
  #pragma unroll
  for (int off = 32; off > 0; off >>= 1) lsum += __shfl_down(lsum, off, 64);
  if (lane == 0) sm[wid] = lsum;
  __syncthreads();
  float inv = 1.0f / (sm[0] + sm[1] + sm[2] + sm[3]);
  if (s0 < S) sc[(size_t)b * S + s0] = expf(a0 - vmax) * inv;
  if (s2 < S) sc[(size_t)b * S + s2] = expf(a1 - vmax) * inv;
}

__global__ __launch_bounds__(256) void k_wpart(const u16* __restrict__ A,
    const float* __restrict__ a, float* __restrict__ wp) {
  int b = blockIdx.x;
  int e2 = blockIdx.y * 256 + threadIdx.x;
  int scn = blockIdx.z;
  const float* arow = a + (size_t)b * SJD;
  float acc0 = 0.f, acc1 = 0.f;
  #pragma unroll 4
  for (int s = scn * 100; s < scn * 100 + 100; ++s) {
    unsigned u = *(const unsigned*)(A + ((size_t)s * BB + b) * E2D + e2 * 2);
    float w = arow[s];
    acc0 += w * bf2f((u16)(u & 0xffff));
    acc1 += w * bf2f((u16)(u >> 16));
  }
  float* dst = wp + ((size_t)scn * BB + b) * E2D + e2 * 2;
  dst[0] = acc0;
  dst[1] = acc1;
}

__global__ __launch_bounds__(256) void k_wsum(const float* __restrict__ wp,
    float* __restrict__ wgt) {
  int i = blockIdx.x * 256 + threadIdx.x;
  const int N = BB * E2D;
  wgt[i] = wp[i] + wp[N + i] + wp[2 * N + i] + wp[3 * N + i];
}

__global__ __launch_bounds__(256) void k_concat_x(const float* __restrict__ emb,
    const float* __restrict__ wgt, float* __restrict__ x) {
  int b = blockIdx.x;
  for (int i = threadIdx.x; i < EMBD + E2D; i += 256)
    x[(size_t)b * (EMBD + E2D) + i] = (i < EMBD) ? emb[(size_t)b * EMBD + i]
                                                 : wgt[(size_t)b * E2D + i - EMBD];
}

// concat + bf16 convert for fc A-side
__global__ __launch_bounds__(256) void k_concat_state_bf(const float* __restrict__ hnew,
    const float* __restrict__ wgt, u16* __restrict__ st) {
  int b = blockIdx.x;
  for (int i = threadIdx.x; i < DECD + E2D; i += 256) {
    float vv = (i < DECD) ? hnew[(size_t)b * DECD + i] : wgt[(size_t)b * E2D + i - DECD];
    st[(size_t)b * (DECD + E2D) + i] = f2bf(vv);
  }
}

// C[128][N] = A[128][K] @ B[N][K]^T + bias  (fp32, used for small GRU gemms)
__global__ __launch_bounds__(256) void gemm_abt(
    const float* __restrict__ A, int lda,
    const float* __restrict__ Bm, int ldb,
    const float* __restrict__ bias,
    float* __restrict__ C, int ldc,
    int N, int K) {
  __shared__ float As[16][132];
  __shared__ float Bs[16][68];
  int tid = threadIdx.x;
  int nb = blockIdx.x * 64;
  int m0 = (tid & 15) * 8;
  int n0 = (tid >> 4) * 4;
  float acc[8][4];
  #pragma unroll
  for (int i = 0; i < 8; ++i)
    #pragma unroll
    for (int j = 0; j < 4; ++j) acc[i][j] = 0.f;
  int lm = tid >> 2;
  int lk = (tid & 3) * 4;
  for (int k0 = 0; k0 < K; k0 += 16) {
    float4 av0 = *(const float4*)&A[(size_t)lm * lda + k0 + lk];
    float4 av1 = *(const float4*)&A[(size_t)(lm + 64) * lda + k0 + lk];
    int gn = nb + lm;
    float4 bv = make_float4(0.f, 0.f, 0.f, 0.f);
    if (gn < N) bv = *(const float4*)&Bm[(size_t)gn * ldb + k0 + lk];
    As[lk + 0][lm] = av0.x; As[lk + 1][lm] = av0.y; As[lk + 2][lm] = av0.z; As[lk + 3][lm] = av0.w;
    As[lk + 0][lm + 64] = av1.x; As[lk + 1][lm + 64] = av1.y; As[lk + 2][lm + 64] = av1.z; As[lk + 3][lm + 64] = av1.w;
    Bs[lk + 0][lm] = bv.x; Bs[lk + 1][lm] = bv.y; Bs[lk + 2][lm] = bv.z; Bs[lk + 3][lm] = bv.w;
    __syncthreads();
    #pragma unroll
    for (int kk = 0; kk < 16; ++kk) {
      float4 a0 = *(const float4*)&As[kk][m0];
      float4 a1 = *(const float4*)&As[kk][m0 + 4];
      float4 bb = *(const float4*)&Bs[kk][n0];
      float am[8] = {a0.x, a0.y, a0.z, a0.w, a1.x, a1.y, a1.z, a1.w};
      float bn[4] = {bb.x, bb.y, bb.z, bb.w};
      #pragma unroll
      for (int i = 0; i < 8; ++i)
        #pragma unroll
        for (int j = 0; j < 4; ++j) acc[i][j] += am[i] * bn[j];
    }
    __syncthreads();
  }
  #pragma unroll
  for (int i = 0; i < 8; ++i) {
    int m = m0 + i;
    #pragma unroll
    for (int j = 0; j < 4; ++j) {
      int gn = nb + n0 + j;
      if (gn < N) C[(size_t)m * ldc + gn] = acc[i][j] + (bias ? bias[gn] : 0.f);
    }
  }
}

__global__ __launch_bounds__(256) void k_gru(const float* __restrict__ gx,
    const float* __restrict__ gh, const float* __restrict__ hidden,
    float* __restrict__ hnew) {
  int b = blockIdx.x, tid = threadIdx.x;
  #pragma unroll
  for (int qq = 0; qq < 2; ++qq) {
    int d = tid + qq * 256;
    size_t o = (size_t)b * 1536;
    float xr = gx[o + d],        hr = gh[o + d];
    float xz = gx[o + 512 + d],  hz = gh[o + 512 + d];
    float xn = gx[o + 1024 + d], hn = gh[o + 1024 + d];
    float r = 1.f / (1.f + expf(-(xr + hr)));
    float z = 1.f / (1.f + expf(-(xz + hz)));
    float n = tanhf(xn + r * hn);
    hnew[(size_t)b * DECD + d] = (1.f - z) * n + z * hidden[(size_t)b * DECD + d];
  }
}

__global__ __launch_bounds__(256) void k_pgen(const float* __restrict__ wgt,
    const float* __restrict__ emb, const float* __restrict__ gW,
    const float* __restrict__ gb, float* __restrict__ pg) {
  int b = blockIdx.x, tid = threadIdx.x;
  __shared__ float sm[4];
  float s = 0.f;
  for (int k = tid; k < E2D + EMBD; k += 256)
    s += gW[k] * ((k < E2D) ? wgt[(size_t)b * E2D + k] : emb[(size_t)b * EMBD + k - E2D]);
  #pragma unroll
  for (int off = 32; off > 0; off >>= 1) s += __shfl_down(s, off, 64);
  int lane = tid & 63, wid = tid >> 6;
  if (lane == 0) sm[wid] = s;
  __syncthreads();
  if (tid == 0) {
    float t = sm[0] + sm[1] + sm[2] + sm[3] + gb[0];
    pg[b] = 1.f / (1.f + expf(-t));
  }
}

__global__ __launch_bounds__(256) void k_vocab(float* __restrict__ dist,
    const float* __restrict__ pg) {
  int b = blockIdx.x, tid = threadIdx.x;
  float* row = dist + (size_t)b * VV;
  __shared__ float sm[4];
  float m = -INFINITY;
  for (int i = tid; i < VV; i += 256) m = fmaxf(m, row[i]);
  #pragma unroll
  for (int off = 32; off > 0; off >>= 1) m = fmaxf(m, __shfl_down(m, off, 64));
  int lane = tid & 63, wid = tid >> 6;
  if (lane == 0) sm[wid] = m;
  __syncthreads();
  m = fmaxf(fmaxf(sm[0], sm[1]), fmaxf(sm[2], sm[3]));
  __syncthreads();
  float s = 0.f;
  for (int i = tid; i < VV; i += 256) s += expf(row[i] - m);
  #pragma unroll
  for (int off = 32; off > 0; off >>= 1) s += __shfl_down(s, off, 64);
  if (lane == 0) sm[wid] = s;
  __syncthreads();
  s = sm[0] + sm[1] + sm[2] + sm[3];
  float scale = pg[b] / s;
  for (int i = tid; i < VV; i += 256) row[i] = expf(row[i] - m) * scale;
}

__global__ __launch_bounds__(256) void k_scatter(float* __restrict__ dist,
    const float* __restrict__ ad, const float* __restrict__ pg,
    const int* __restrict__ src1) {
  int b = blockIdx.x, tid = threadIdx.x;
  if (tid < S1D) {
    float val = (1.f - pg[b]) * ad[(size_t)b * S1D + tid];
    int tok = src1[(size_t)tid * BB + b];
    atomicAdd(&dist[(size_t)b * VV + tok], val);
  }
}

extern "C" void kernel_launch(void* const* d_in, const int* in_sizes, int n_in,
                              void* d_out, int out_size, void* d_ws, size_t ws_size,
                              hipStream_t stream) {
  (void)in_sizes; (void)n_in; (void)out_size; (void)ws_size;
  const int*   input  = (const int*)d_in[0];
  const float* hidden = (const float*)d_in[1];
  const int*   src1   = (const int*)d_in[2];
  const float* enc1   = (const float*)d_in[3];
  const int*   mask1  = (const int*)d_in[4];
  const int*   triple = (const int*)d_in[5];
  const float* enc2   = (const float*)d_in[6];
  const int*   mask2  = (const int*)d_in[7];
  const float* embedding = (const float*)d_in[8];
  const float* attn_W = (const float*)d_in[9];
  const float* attn_b = (const float*)d_in[10];
  const float* attn_v = (const float*)d_in[11];
  const float* copy_W = (const float*)d_in[12];
  const float* copy_b = (const float*)d_in[13];
  const float* copy_v = (const float*)d_in[14];
  const float* gru_Wih = (const float*)d_in[15];
  const float* gru_Whh = (const float*)d_in[16];
  const float* gru_bih = (const float*)d_in[17];
  const float* gru_bhh = (const float*)d_in[18];
  const float* fc_W   = (const float*)d_in[19];
  const float* fc_b   = (const float*)d_in[20];
  const float* gate_W = (const float*)d_in[21];
  const float* gate_b = (const float*)d_in[22];

  char* w = (char*)d_ws;
  u16* A_bf = (u16*)w;                w += (size_t)51200 * 1024 * 2;
  u16* Wt_a = (u16*)w;                w += (size_t)512 * 1024 * 2;
  u16* Wt_c = (u16*)w;                w += (size_t)512 * 1024 * 2;
  float* partJ = (float*)w;           w += (size_t)4 * 51200 * 4;
  float* partC = (float*)w;           w += (size_t)4 * 25600 * 4;
  float* emb  = (float*)w;            w += (size_t)BB * EMBD * 4;
  float* hWa  = (float*)w;            w += (size_t)BB * DECD * 4;
  float* hWc  = (float*)w;            w += (size_t)BB * DECD * 4;
  float* scJ  = (float*)w;            w += (size_t)BB * SJD * 4;
  float* scC  = (float*)w;            w += (size_t)BB * S1D * 4;
  float* wgt  = (float*)w;            w += (size_t)BB * E2D * 4;
  float* wpart = (float*)w;           w += (size_t)4 * BB * E2D * 4;
  float* x    = (float*)w;            w += (size_t)BB * 1280 * 4;
  float* gx   = (float*)w;            w += (size_t)BB * 1536 * 4;
  float* gh   = (float*)w;            w += (size_t)BB * 1536 * 4;
  u16*   st_bf = (u16*)w;             w += (size_t)BB * 1536 * 2;
  float* pg   = (float*)w;            w += 512;

  float* out  = (float*)d_out;
  float* hnew = out + (size_t)BB * VV;

  // conversions
  k_cvt<<<12800, 256, 0, stream>>>(enc1, A_bf, 25600 * 1024 / 8);
  k_cvt<<<12800, 256, 0, stream>>>(enc2, A_bf + (size_t)25600 * 1024, 25600 * 1024 / 8);
  k_wt<<<dim3(32, 16), 256, 0, stream>>>(attn_W, Wt_a);
  k_wt<<<dim3(32, 16), 256, 0, stream>>>(copy_W, Wt_c);

  k_emb<<<BB, 256, 0, stream>>>(input, embedding, emb);
  k_partial<<<dim3(2, BB), 256, 0, stream>>>(hidden, attn_W, attn_b, hWa);

  // joint attention scores
  gemm_energy<<<dim3(400, 4), 256, 0, stream>>>(A_bf, Wt_a, hWa, attn_v, partJ, 51200);
  k_sum4<<<200, 256, 0, stream>>>(partJ, scJ, 51200, SJD);
  k_softmax_s<<<BB, 256, 0, stream>>>(scJ, SJD, mask1, mask2, 0);

  // weighted context
  k_wpart<<<dim3(BB, 2, 4), 256, 0, stream>>>(A_bf, scJ, wpart);
  k_wsum<<<512, 256, 0, stream>>>(wpart, wgt);

  // GRU
  k_concat_x<<<BB, 256, 0, stream>>>(emb, wgt, x);
  gemm_abt<<<1536 / 64, 256, 0, stream>>>(x, 1280, gru_Wih, 1280, gru_bih, gx, 1536, 1536, 1280);
  gemm_abt<<<1536 / 64, 256, 0, stream>>>(hidden, 512, gru_Whh, 512, gru_bhh, gh, 1536, 1536, 512);
  k_gru<<<BB, 256, 0, stream>>>(gx, gh, hidden, hnew);

  // vocab logits (MFMA, fused fp32->bf16 of fc_W)
  k_concat_state_bf<<<BB, 256, 0, stream>>>(hnew, wgt, st_bf);
  gemm_fc<<<(VV + 63) / 64, 256, 0, stream>>>(st_bf, fc_W, fc_b, out, VV, 1536);

  // copy path
  k_pgen<<<BB, 256, 0, stream>>>(wgt, emb, gate_W, gate_b, pg);
  k_partial<<<dim3(2, BB), 256, 0, stream>>>(hnew, copy_W, copy_b, hWc);
  gemm_energy<<<dim3(200, 4), 256, 0, stream>>>(A_bf, Wt_c, hWc, copy_v, partC, 25600);
  k_sum4<<<100, 256, 0, stream>>>(partC, scC, 25600, S1D);
  k_softmax_s<<<BB, 256, 0, stream>>>(scC, S1D, mask1, triple, 1);

  // final distribution
  k_vocab<<<BB, 256, 0, stream>>>(out, pg);
  k_scatter<<<BB, 256, 0, stream>>>(out, scC, pg, src1);
}

// Round 4
// 666.446 us; speedup vs baseline: 3.5991x; 1.1181x over previous
//
#include <hip/hip_runtime.h>
#include <math.h>

#define BB   128
#define DECD 512
#define E2D  1024
#define EMBD 256
#define S1D  200
#define S2D  200
#define SJD  400
#define VV   50000
#define NEGV (-1e10f)

typedef unsigned short u16;
typedef __bf16 bf16x8 __attribute__((ext_vector_type(8)));
typedef float f32x4 __attribute__((ext_vector_type(4)));
typedef u16 u16x8 __attribute__((ext_vector_type(8)));

__device__ __forceinline__ u16 f2bf(float x) {
  unsigned u = __float_as_uint(x);
  unsigned r = (u + 0x7fffu + ((u >> 16) & 1u)) >> 16;
  return (u16)r;
}
__device__ __forceinline__ float bf2f(u16 h) {
  return __uint_as_float(((unsigned)h) << 16);
}

typedef const __attribute__((address_space(1))) void* gas_t;
typedef __attribute__((address_space(3))) void* las_t;
__device__ __forceinline__ void async_copy16(const u16* g, u16* l) {
  __builtin_amdgcn_global_load_lds((gas_t)g, (las_t)l, 16, 0, 0);
}

// ---------------- generic fp32 -> bf16 ----------------
__global__ __launch_bounds__(256) void k_cvt(const float* __restrict__ src,
    u16* __restrict__ dst, int n8) {
  int i = blockIdx.x * 256 + threadIdx.x;
  if (i >= n8) return;
  const float4 f0 = *(const float4*)(src + (size_t)i * 8);
  const float4 f1 = *(const float4*)(src + (size_t)i * 8 + 4);
  u16x8 o;
  o[0] = f2bf(f0.x); o[1] = f2bf(f0.y); o[2] = f2bf(f0.z); o[3] = f2bf(f0.w);
  o[4] = f2bf(f1.x); o[5] = f2bf(f1.y); o[6] = f2bf(f1.z); o[7] = f2bf(f1.w);
  *(u16x8*)(dst + (size_t)i * 8) = o;
}

// Wt[n][k] = bf16( W[512+k][n] )
__global__ __launch_bounds__(256) void k_wt(const float* __restrict__ W,
    u16* __restrict__ Wt) {
  __shared__ float t[32][33];
  int bk = blockIdx.x, bn = blockIdx.y;
  int tx = threadIdx.x & 31, ty = threadIdx.x >> 5;
  #pragma unroll
  for (int r = 0; r < 4; ++r) {
    int k = bk * 32 + ty + r * 8;
    t[ty + r * 8][tx] = W[(size_t)(512 + k) * 512 + bn * 32 + tx];
  }
  __syncthreads();
  #pragma unroll
  for (int r = 0; r < 4; ++r) {
    int n = bn * 32 + ty + r * 8;
    Wt[(size_t)n * 1024 + bk * 32 + tx] = f2bf(t[tx][ty + r * 8]);
  }
}

// ---------------- 8-wave fused energy GEMM ----------------
// One block per s-tile (128 rows), full N=512 in-block.
// CONV=1: A from fp32 enc (reg-staged, converted, also written to Abf_out).
// CONV=0: A from bf16 Abf_in via global_load_lds.
template<int CONV>
__global__ __launch_bounds__(512) void gemm_energy8(
    const float* __restrict__ enc1, const float* __restrict__ enc2,
    const u16* __restrict__ Abf_in, u16* __restrict__ Abf_out,
    const u16* __restrict__ Bt,
    const float* __restrict__ hW, const float* __restrict__ v,
    float* __restrict__ scores, int sldS) {
  __shared__ u16 As[128 * 32];
  __shared__ u16 Bs[512 * 32];
  __shared__ float sbuf[128][4];
  int tid = threadIdx.x;
  int wid = tid >> 6, lane = tid & 63;
  int wr = wid >> 2, wc = wid & 3;
  int sidx = blockIdx.x;
  size_t m0 = (size_t)sidx * 128;

  // ---- A staging setup ----
  int rA = tid >> 2, cslot = tid & 3;
  const float* gA_f = nullptr;
  const u16*   gA_b = nullptr;
  u16*         gA_o = nullptr;
  u16* lA_w = As + rA * 32 + (cslot ^ ((rA >> 1) & 3)) * 8;   // reg path (swizzled slot)
  u16* lA_async = As + wid * 512;                             // async path (wave-uniform)
  if (CONV) {
    const float* base = (sidx < S1D) ? (enc1 + m0 * E2D)
                                     : (enc2 + (m0 - (size_t)S1D * BB) * E2D);
    gA_f = base + (size_t)rA * E2D + cslot * 8;
    gA_o = Abf_out + (m0 + rA) * E2D + cslot * 8;
  } else {
    int cs = cslot ^ ((rA >> 1) & 3);                          // pre-swizzled source
    gA_b = Abf_in + (m0 + rA) * E2D + cs * 8;
  }

  // ---- B staging (4 async issues, 512 rows x 32 cols bf16) ----
  const u16* gB[4]; u16* lB[4];
  #pragma unroll
  for (int i = 0; i < 4; ++i) {
    int idx = i * 512 + tid;
    int rn = idx >> 2;
    int c = (idx & 3) ^ ((rn >> 1) & 3);
    gB[i] = Bt + (size_t)rn * E2D + c * 8;
    lB[i] = Bs + i * 4096 + wid * 512;
  }

  // ---- fragment offsets ----
  int q = lane >> 4, cl = lane & 15;
  int aoff[4], boff[8];
  #pragma unroll
  for (int mi = 0; mi < 4; ++mi) {
    int row = wr * 64 + mi * 16 + cl;
    aoff[mi] = row * 64 + ((q ^ ((row >> 1) & 3)) * 16);
  }
  #pragma unroll
  for (int nj = 0; nj < 8; ++nj) {
    int rn = wc * 128 + nj * 16 + cl;
    boff[nj] = rn * 64 + ((q ^ ((rn >> 1) & 3)) * 16);
  }

  f32x4 acc[4][8];
  #pragma unroll
  for (int mi = 0; mi < 4; ++mi)
    #pragma unroll
    for (int nj = 0; nj < 8; ++nj) {
      f32x4 z = {0.f, 0.f, 0.f, 0.f};
      acc[mi][nj] = z;
    }

  float4 a0, a1;
  if (CONV) { a0 = *(const float4*)gA_f; a1 = *(const float4*)(gA_f + 4); }

  for (int k0 = 0; k0 < 1024; k0 += 32) {
    if (CONV) {
      u16x8 ob;
      ob[0] = f2bf(a0.x); ob[1] = f2bf(a0.y); ob[2] = f2bf(a0.z); ob[3] = f2bf(a0.w);
      ob[4] = f2bf(a1.x); ob[5] = f2bf(a1.y); ob[6] = f2bf(a1.z); ob[7] = f2bf(a1.w);
      *(u16x8*)lA_w = ob;
      *(u16x8*)(gA_o + k0) = ob;
    } else {
      async_copy16(gA_b + k0, lA_async);
    }
    #pragma unroll
    for (int i = 0; i < 4; ++i) async_copy16(gB[i] + k0, lB[i]);
    __syncthreads();
    if (CONV && k0 + 32 < 1024) {       // prefetch next A under MFMA phase
      a0 = *(const float4*)(gA_f + k0 + 32);
      a1 = *(const float4*)(gA_f + k0 + 36);
    }
    bf16x8 af[4], bg[8];
    #pragma unroll
    for (int mi = 0; mi < 4; ++mi)
      af[mi] = *(const bf16x8*)((const char*)As + aoff[mi]);
    #pragma unroll
    for (int nj = 0; nj < 8; ++nj)
      bg[nj] = *(const bf16x8*)((const char*)Bs + boff[nj]);
    #pragma unroll
    for (int mi = 0; mi < 4; ++mi)
      #pragma unroll
      for (int nj = 0; nj < 8; ++nj)
        acc[mi][nj] = __builtin_amdgcn_mfma_f32_16x16x32_bf16(af[mi], bg[nj], acc[mi][nj], 0, 0, 0);
    __syncthreads();
  }

  // ---- epilogue: sum_d tanh(acc + hW)*v ----
  #pragma unroll
  for (int mi = 0; mi < 4; ++mi) {
    #pragma unroll
    for (int j = 0; j < 4; ++j) {
      int m = wr * 64 + mi * 16 + q * 4 + j;
      float s = 0.f;
      #pragma unroll
      for (int nj = 0; nj < 8; ++nj) {
        int d = wc * 128 + nj * 16 + cl;
        s += tanhf(acc[mi][nj][j] + hW[(size_t)m * DECD + d]) * v[d];
      }
      s += __shfl_xor(s, 1, 64);
      s += __shfl_xor(s, 2, 64);
      s += __shfl_xor(s, 4, 64);
      s += __shfl_xor(s, 8, 64);
      if (cl == 0) sbuf[m][wc] = s;
    }
  }
  __syncthreads();
  if (tid < 128)
    scores[(size_t)tid * sldS + sidx] = sbuf[tid][0] + sbuf[tid][1] + sbuf[tid][2] + sbuf[tid][3];
}

// ---------------- MFMA A@B^T with fused fp32->bf16 of B, 2-deep B pipeline ----------------
// C[128][N] = A_bf[128][K] @ bf16(Bf[N][K])^T + bias.  K % 64 == 0.
__global__ __launch_bounds__(256) void gemm_fc(
    const u16* __restrict__ A, const float* __restrict__ Bf,
    const float* __restrict__ bias, float* __restrict__ C,
    int N, int K) {
  __shared__ u16 As[128 * 32];
  __shared__ u16 Bs[64 * 32];
  int tid = threadIdx.x;
  int wid = tid >> 6, lane = tid & 63;
  int wr = wid >> 1, wc = wid & 1;
  int n0 = blockIdx.x * 64;

  int idx0 = tid, idx1 = tid + 256;
  int rA0 = idx0 >> 2, cA0 = (idx0 & 3) ^ ((rA0 >> 1) & 3);
  int rA1 = idx1 >> 2, cA1 = (idx1 & 3) ^ ((rA1 >> 1) & 3);
  const u16* gA0 = A + (size_t)rA0 * K + cA0 * 8;
  const u16* gA1 = A + (size_t)rA1 * K + cA1 * 8;
  u16* lA0 = As + wid * 512;
  u16* lA1 = As + 2048 + wid * 512;

  int rB = tid >> 2, cB = tid & 3;
  int gnB = n0 + rB; if (gnB >= N) gnB = N - 1;
  const float* gB = Bf + (size_t)gnB * K + cB * 8;
  u16* lBp = Bs + rB * 32 + (cB ^ ((rB >> 1) & 3)) * 8;

  int q = lane >> 4, cl = lane & 15;
  int aoff[4], boff[2];
  #pragma unroll
  for (int mi = 0; mi < 4; ++mi) {
    int row = wr * 64 + mi * 16 + cl;
    aoff[mi] = row * 64 + ((q ^ ((row >> 1) & 3)) * 16);
  }
  #pragma unroll
  for (int nj = 0; nj < 2; ++nj) {
    int rn = wc * 32 + nj * 16 + cl;
    boff[nj] = rn * 64 + ((q ^ ((rn >> 1) & 3)) * 16);
  }

  f32x4 acc[4][2];
  #pragma unroll
  for (int mi = 0; mi < 4; ++mi)
    #pragma unroll
    for (int nj = 0; nj < 2; ++nj) {
      f32x4 z = {0.f, 0.f, 0.f, 0.f};
      acc[mi][nj] = z;
    }

  float4 p0 = *(const float4*)(gB),      p1 = *(const float4*)(gB + 4);
  float4 q0 = *(const float4*)(gB + 32), q1 = *(const float4*)(gB + 36);

  for (int k0 = 0; k0 < K; k0 += 64) {
    // ---- phase 0: K-chunk k0 (regs p) ----
    {
      u16x8 ob;
      ob[0] = f2bf(p0.x); ob[1] = f2bf(p0.y); ob[2] = f2bf(p0.z); ob[3] = f2bf(p0.w);
      ob[4] = f2bf(p1.x); ob[5] = f2bf(p1.y); ob[6] = f2bf(p1.z); ob[7] = f2bf(p1.w);
      *(u16x8*)lBp = ob;
      async_copy16(gA0 + k0, lA0);
      async_copy16(gA1 + k0, lA1);
      __syncthreads();
      if (k0 + 64 < K) { p0 = *(const float4*)(gB + k0 + 64); p1 = *(const float4*)(gB + k0 + 68); }
      bf16x8 af[4], bg[2];
      #pragma unroll
      for (int mi = 0; mi < 4; ++mi) af[mi] = *(const bf16x8*)((const char*)As + aoff[mi]);
      #pragma unroll
      for (int nj = 0; nj < 2; ++nj) bg[nj] = *(const bf16x8*)((const char*)Bs + boff[nj]);
      #pragma unroll
      for (int mi = 0; mi < 4; ++mi)
        #pragma unroll
        for (int nj = 0; nj < 2; ++nj)
          acc[mi][nj] = __builtin_amdgcn_mfma_f32_16x16x32_bf16(af[mi], bg[nj], acc[mi][nj], 0, 0, 0);
      __syncthreads();
    }
    // ---- phase 1: K-chunk k0+32 (regs q) ----
    {
      u16x8 ob;
      ob[0] = f2bf(q0.x); ob[1] = f2bf(q0.y); ob[2] = f2bf(q0.z); ob[3] = f2bf(q0.w);
      ob[4] = f2bf(q1.x); ob[5] = f2bf(q1.y); ob[6] = f2bf(q1.z); ob[7] = f2bf(q1.w);
      *(u16x8*)lBp = ob;
      async_copy16(gA0 + k0 + 32, lA0);
      async_copy16(gA1 + k0 + 32, lA1);
      __syncthreads();
      if (k0 + 96 < K) { q0 = *(const float4*)(gB + k0 + 96); q1 = *(const float4*)(gB + k0 + 100); }
      bf16x8 af[4], bg[2];
      #pragma unroll
      for (int mi = 0; mi < 4; ++mi) af[mi] = *(const bf16x8*)((const char*)As + aoff[mi]);
      #pragma unroll
      for (int nj = 0; nj < 2; ++nj) bg[nj] = *(const bf16x8*)((const char*)Bs + boff[nj]);
      #pragma unroll
      for (int mi = 0; mi < 4; ++mi)
        #pragma unroll
        for (int nj = 0; nj < 2; ++nj)
          acc[mi][nj] = __builtin_amdgcn_mfma_f32_16x16x32_bf16(af[mi], bg[nj], acc[mi][nj], 0, 0, 0);
      __syncthreads();
    }
  }

  #pragma unroll
  for (int mi = 0; mi < 4; ++mi) {
    #pragma unroll
    for (int nj = 0; nj < 2; ++nj) {
      int n = n0 + wc * 32 + nj * 16 + cl;
      if (n < N) {
        float bv = bias[n];
        #pragma unroll
        for (int j = 0; j < 4; ++j) {
          int m = wr * 64 + mi * 16 + q * 4 + j;
          C[(size_t)m * N + n] = acc[mi][nj][j] + bv;
        }
      }
    }
  }
}

// ---------------- small kernels ----------------
__global__ __launch_bounds__(256) void k_partial(const float* __restrict__ h,
    const float* __restrict__ W, const float* __restrict__ bias,
    float* __restrict__ out) {
  int b = blockIdx.y;
  int d = blockIdx.x * 256 + threadIdx.x;
  const float* hr = h + (size_t)b * DECD;
  float acc = bias[d];
  #pragma unroll 8
  for (int k = 0; k < DECD; ++k) acc += hr[k] * W[(size_t)k * DECD + d];
  out[(size_t)b * DECD + d] = acc;
}

__global__ __launch_bounds__(256) void k_softmax_s(float* __restrict__ sc, int S,
    const int* __restrict__ m1, const int* __restrict__ m2, int mode) {
  int b = blockIdx.x, tid = threadIdx.x;
  __shared__ float sm[4];
  int s0 = tid, s2 = tid + 256;
  float a0 = -INFINITY, a1 = -INFINITY;
  if (s0 < S) {
    int msk = (mode == 0) ? ((s0 < S1D) ? m1[b * S1D + s0] : m2[b * S2D + (s0 - S1D)])
                          : (m1[b * S1D + s0] * m2[b * S1D + s0]);
    a0 = msk ? sc[(size_t)b * S + s0] : NEGV;
  }
  if (s2 < S) {
    int msk = (mode == 0) ? ((s2 < S1D) ? m1[b * S1D + s2] : m2[b * S2D + (s2 - S1D)])
                          : (m1[b * S1D + s2] * m2[b * S1D + s2]);
    a1 = msk ? sc[(size_t)b * S + s2] : NEGV;
  }
  float vmax = fmaxf(a0, a1);
  #pragma unroll
  for (int off = 32; off > 0; off >>= 1) vmax = fmaxf(vmax, __shfl_down(vmax, off, 64));
  int lane = tid & 63, wid = tid >> 6;
  if (lane == 0) sm[wid] = vmax;
  __syncthreads();
  vmax = fmaxf(fmaxf(sm[0], sm[1]), fmaxf(sm[2], sm[3]));
  __syncthreads();
  float lsum = 0.f;
  if (s0 < S) lsum += expf(a0 - vmax);
  if (s2 < S) lsum += expf(a1 - vmax);
  #pragma unroll
  for (int off = 32; off > 0; off >>= 1) lsum += __shfl_down(lsum, off, 64);
  if (lane == 0) sm[wid] = lsum;
  __syncthreads();
  float inv = 1.0f / (sm[0] + sm[1] + sm[2] + sm[3]);
  if (s0 < S) sc[(size_t)b * S + s0] = expf(a0 - vmax) * inv;
  if (s2 < S) sc[(size_t)b * S + s2] = expf(a1 - vmax) * inv;
}

__global__ __launch_bounds__(256) void k_wpart(const u16* __restrict__ A,
    const float* __restrict__ a, float* __restrict__ wp) {
  int b = blockIdx.x;
  int e2 = blockIdx.y * 256 + threadIdx.x;
  int scn = blockIdx.z;
  const float* arow = a + (size_t)b * SJD;
  float acc0 = 0.f, acc1 = 0.f;
  #pragma unroll 4
  for (int s = scn * 100; s < scn * 100 + 100; ++s) {
    unsigned u = *(const unsigned*)(A + ((size_t)s * BB + b) * E2D + e2 * 2);
    float w = arow[s];
    acc0 += w * bf2f((u16)(u & 0xffff));
    acc1 += w * bf2f((u16)(u >> 16));
  }
  float* dst = wp + ((size_t)scn * BB + b) * E2D + e2 * 2;
  dst[0] = acc0;
  dst[1] = acc1;
}

// sum 4 partials -> wgt (fp32) and x_bf tail (bf16)
__global__ __launch_bounds__(256) void k_wsum_x(const float* __restrict__ wp,
    float* __restrict__ wgt, u16* __restrict__ x) {
  int i = blockIdx.x * 256 + threadIdx.x;
  const int NN = BB * E2D;
  float s = wp[i] + wp[NN + i] + wp[2 * NN + i] + wp[3 * NN + i];
  wgt[i] = s;
  int b = i >> 10, e = i & 1023;
  x[(size_t)b * 1280 + EMBD + e] = f2bf(s);
}

// embedding gather -> x_bf head
__global__ __launch_bounds__(256) void k_embx(const int* __restrict__ inp,
    const float* __restrict__ table, u16* __restrict__ x) {
  int b = blockIdx.x, t = threadIdx.x;
  x[(size_t)b * 1280 + t] = f2bf(table[(size_t)inp[b] * EMBD + t]);
}

__global__ __launch_bounds__(256) void k_concat_state_bf(const float* __restrict__ hnew,
    const float* __restrict__ wgt, u16* __restrict__ st) {
  int b = blockIdx.x;
  for (int i = threadIdx.x; i < DECD + E2D; i += 256) {
    float vv = (i < DECD) ? hnew[(size_t)b * DECD + i] : wgt[(size_t)b * E2D + i - DECD];
    st[(size_t)b * (DECD + E2D) + i] = f2bf(vv);
  }
}

__global__ __launch_bounds__(256) void k_gru(const float* __restrict__ gx,
    const float* __restrict__ gh, const float* __restrict__ hidden,
    float* __restrict__ hnew) {
  int b = blockIdx.x, tid = threadIdx.x;
  #pragma unroll
  for (int qq = 0; qq < 2; ++qq) {
    int d = tid + qq * 256;
    size_t o = (size_t)b * 1536;
    float xr = gx[o + d],        hr = gh[o + d];
    float xz = gx[o + 512 + d],  hz = gh[o + 512 + d];
    float xn = gx[o + 1024 + d], hn = gh[o + 1024 + d];
    float r = 1.f / (1.f + expf(-(xr + hr)));
    float z = 1.f / (1.f + expf(-(xz + hz)));
    float n = tanhf(xn + r * hn);
    hnew[(size_t)b * DECD + d] = (1.f - z) * n + z * hidden[(size_t)b * DECD + d];
  }
}

__global__ __launch_bounds__(256) void k_pgen(const float* __restrict__ wgt,
    const int* __restrict__ inp, const float* __restrict__ table,
    const float* __restrict__ gW, const float* __restrict__ gb,
    float* __restrict__ pg) {
  int b = blockIdx.x, tid = threadIdx.x;
  __shared__ float sm[4];
  float s = 0.f;
  for (int k = tid; k < E2D + EMBD; k += 256)
    s += gW[k] * ((k < E2D) ? wgt[(size_t)b * E2D + k]
                            : table[(size_t)inp[b] * EMBD + k - E2D]);
  #pragma unroll
  for (int off = 32; off > 0; off >>= 1) s += __shfl_down(s, off, 64);
  int lane = tid & 63, wid = tid >> 6;
  if (lane == 0) sm[wid] = s;
  __syncthreads();
  if (tid == 0) {
    float t = sm[0] + sm[1] + sm[2] + sm[3] + gb[0];
    pg[b] = 1.f / (1.f + expf(-t));
  }
}

__global__ __launch_bounds__(256) void k_vocab(float* __restrict__ dist,
    const float* __restrict__ pg) {
  int b = blockIdx.x, tid = threadIdx.x;
  float* row = dist + (size_t)b * VV;
  __shared__ float sm[4];
  float m = -INFINITY;
  for (int i = tid; i < VV; i += 256) m = fmaxf(m, row[i]);
  #pragma unroll
  for (int off = 32; off > 0; off >>= 1) m = fmaxf(m, __shfl_down(m, off, 64));
  int lane = tid & 63, wid = tid >> 6;
  if (lane == 0) sm[wid] = m;
  __syncthreads();
  m = fmaxf(fmaxf(sm[0], sm[1]), fmaxf(sm[2], sm[3]));
  __syncthreads();
  float s = 0.f;
  for (int i = tid; i < VV; i += 256) s += expf(row[i] - m);
  #pragma unroll
  for (int off = 32; off > 0; off >>= 1) s += __shfl_down(s, off, 64);
  if (lane == 0) sm[wid] = s;
  __syncthreads();
  s = sm[0] + sm[1] + sm[2] + sm[3];
  float scale = pg[b] / s;
  for (int i = tid; i < VV; i += 256) row[i] = expf(row[i] - m) * scale;
}

__global__ __launch_bounds__(256) void k_scatter(float* __restrict__ dist,
    const float* __restrict__ ad, const float* __restrict__ pg,
    const int* __restrict__ src1) {
  int b = blockIdx.x, tid = threadIdx.x;
  if (tid < S1D) {
    float val = (1.f - pg[b]) * ad[(size_t)b * S1D + tid];
    int tok = src1[(size_t)tid * BB + b];
    atomicAdd(&dist[(size_t)b * VV + tok], val);
  }
}

extern "C" void kernel_launch(void* const* d_in, const int* in_sizes, int n_in,
                              void* d_out, int out_size, void* d_ws, size_t ws_size,
                              hipStream_t stream) {
  (void)in_sizes; (void)n_in; (void)out_size; (void)ws_size;
  const int*   input  = (const int*)d_in[0];
  const float* hidden = (const float*)d_in[1];
  const int*   src1   = (const int*)d_in[2];
  const float* enc1   = (const float*)d_in[3];
  const int*   mask1  = (const int*)d_in[4];
  const int*   triple = (const int*)d_in[5];
  const float* enc2   = (const float*)d_in[6];
  const int*   mask2  = (const int*)d_in[7];
  const float* embedding = (const float*)d_in[8];
  const float* attn_W = (const float*)d_in[9];
  const float* attn_b = (const float*)d_in[10];
  const float* attn_v = (const float*)d_in[11];
  const float* copy_W = (const float*)d_in[12];
  const float* copy_b = (const float*)d_in[13];
  const float* copy_v = (const float*)d_in[14];
  const float* gru_Wih = (const float*)d_in[15];
  const float* gru_Whh = (const float*)d_in[16];
  const float* gru_bih = (const float*)d_in[17];
  const float* gru_bhh = (const float*)d_in[18];
  const float* fc_W   = (const float*)d_in[19];
  const float* fc_b   = (const float*)d_in[20];
  const float* gate_W = (const float*)d_in[21];
  const float* gate_b = (const float*)d_in[22];

  char* w = (char*)d_ws;
  u16* A_bf = (u16*)w;                w += (size_t)51200 * 1024 * 2;
  u16* Wt_a = (u16*)w;                w += (size_t)512 * 1024 * 2;
  u16* Wt_c = (u16*)w;                w += (size_t)512 * 1024 * 2;
  float* hWa  = (float*)w;            w += (size_t)BB * DECD * 4;
  float* hWc  = (float*)w;            w += (size_t)BB * DECD * 4;
  float* scJ  = (float*)w;            w += (size_t)BB * SJD * 4;
  float* scC  = (float*)w;            w += (size_t)BB * S1D * 4;
  float* wgt  = (float*)w;            w += (size_t)BB * E2D * 4;
  float* wpart = (float*)w;           w += (size_t)4 * BB * E2D * 4;
  u16*   x_bf = (u16*)w;              w += (size_t)BB * 1280 * 2;
  u16*   hid_bf = (u16*)w;            w += (size_t)BB * DECD * 2;
  float* gx   = (float*)w;            w += (size_t)BB * 1536 * 4;
  float* gh   = (float*)w;            w += (size_t)BB * 1536 * 4;
  u16*   st_bf = (u16*)w;             w += (size_t)BB * 1536 * 2;
  float* pg   = (float*)w;            w += 512;

  float* out  = (float*)d_out;
  float* hnew = out + (size_t)BB * VV;

  // prep
  k_wt<<<dim3(32, 16), 256, 0, stream>>>(attn_W, Wt_a);
  k_wt<<<dim3(32, 16), 256, 0, stream>>>(copy_W, Wt_c);
  k_cvt<<<32, 256, 0, stream>>>(hidden, hid_bf, BB * DECD / 8);
  k_partial<<<dim3(2, BB), 256, 0, stream>>>(hidden, attn_W, attn_b, hWa);
  k_embx<<<BB, 256, 0, stream>>>(input, embedding, x_bf);

  // joint attention scores (+ enc -> bf16 conversion side effect)
  gemm_energy8<1><<<SJD, 512, 0, stream>>>(enc1, enc2, nullptr, A_bf, Wt_a, hWa, attn_v, scJ, SJD);
  k_softmax_s<<<BB, 256, 0, stream>>>(scJ, SJD, mask1, mask2, 0);

  // weighted context
  k_wpart<<<dim3(BB, 2, 4), 256, 0, stream>>>(A_bf, scJ, wpart);
  k_wsum_x<<<512, 256, 0, stream>>>(wpart, wgt, x_bf);

  // GRU (bf16 MFMA with fused weight conversion)
  gemm_fc<<<1536 / 64, 256, 0, stream>>>(x_bf, gru_Wih, gru_bih, gx, 1536, 1280);
  gemm_fc<<<1536 / 64, 256, 0, stream>>>(hid_bf, gru_Whh, gru_bhh, gh, 1536, 512);
  k_gru<<<BB, 256, 0, stream>>>(gx, gh, hidden, hnew);

  // vocab logits
  k_concat_state_bf<<<BB, 256, 0, stream>>>(hnew, wgt, st_bf);
  gemm_fc<<<(VV + 63) / 64, 256, 0, stream>>>(st_bf, fc_W, fc_b, out, VV, 1536);

  // copy path
  k_pgen<<<BB, 256, 0, stream>>>(wgt, input, embedding, gate_W, gate_b, pg);
  k_partial<<<dim3(2, BB), 256, 0, stream>>>(hnew, copy_W, copy_b, hWc);
  gemm_energy8<0><<<S1D, 512, 0, stream>>>(nullptr, nullptr, A_bf, nullptr, Wt_c, hWc, copy_v, scC, S1D);
  k_softmax_s<<<BB, 256, 0, stream>>>(scC, S1D, mask1, triple, 1);

  // final distribution
  k_vocab<<<BB, 256, 0, stream>>>(out, pg);
  k_scatter<<<BB, 256, 0, stream>>>(out, scC, pg, src1);
}